// Round 5
// baseline (5891.195 us; speedup 1.0000x reference)
//
#include <hip/hip_runtime.h>
#include <math.h>

// Problem constants (ViT-Base-ish)
#define BATCH 8
#define CIN 3
#define HIMG 256
#define WIMG 256
#define PATCH 8
#define DMODEL 768
#define DEPTH 8
#define HEADS 12
#define DHEAD 64
#define MLPDIM 3072
#define NTOK 1024              // (256/8)^2
#define INNER 768              // HEADS*DHEAD
#define MROWS (BATCH * NTOK)   // 8192
#define QKVS (3 * INNER)       // 2304
#define KPATCH (CIN * PATCH * PATCH)  // 192
#define LNEPS 1e-5f
#define PSTR 72                // attn LDS row stride (16B-aligned, conflict-safe)
// 0.125 (dh^-0.5) * log2(e): folded into Q so softmax uses exp2 (v_exp_f32)
#define QSCALE 0.18033688011112042f

typedef __attribute__((ext_vector_type(8))) short short8;  // 8 bf16 (4 VGPRs)
typedef __attribute__((ext_vector_type(4))) float v4f;     // MFMA accumulator

__device__ __forceinline__ float b2f(unsigned short u) {
  union { unsigned int i; float f; } x;
  x.i = (unsigned int)u << 16;
  return x.f;
}
__device__ __forceinline__ unsigned short f2b(float f) {
  union { float f; unsigned int i; } x;
  x.f = f;
  unsigned int r = x.i + 0x7FFFu + ((x.i >> 16) & 1u);  // RNE
  return (unsigned short)(r >> 16);
}
// pack 2 fp32 -> 2 bf16 in one u32, round-half-up (cheap: 4 VALU)
__device__ __forceinline__ unsigned int pkrh(float a, float b) {
  union { float f; unsigned int u; } x, y;
  x.f = a; y.f = b;
  return ((x.u + 0x8000u) >> 16) | ((y.u + 0x8000u) & 0xFFFF0000u);
}

// ---------------------------------------------------------------------------
// elementwise fp32 -> bf16 cast (w_conv: [768,192] already [N,K])
__global__ __launch_bounds__(256) void cast_kernel(
    const float* __restrict__ src, unsigned short* __restrict__ dst, int n) {
  int i = blockIdx.x * 256 + threadIdx.x;
  if (i < n) dst[i] = f2b(src[i]);
}

// transpose-cast: src fp32 [R,C] -> dst bf16 [C,R]. R,C multiples of 32.
__global__ __launch_bounds__(256) void transpose_cast_kernel(
    const float* __restrict__ src, unsigned short* __restrict__ dst, int R,
    int C) {
  __shared__ unsigned short t[32][33];
  int c0 = blockIdx.x * 32, r0 = blockIdx.y * 32;
  int tx = threadIdx.x & 31, ty = threadIdx.x >> 5;  // 32 x 8
#pragma unroll
  for (int u = 0; u < 4; ++u) {
    int r = r0 + ty + u * 8;
    t[ty + u * 8][tx] = f2b(src[(size_t)r * C + c0 + tx]);
  }
  __syncthreads();
#pragma unroll
  for (int u = 0; u < 4; ++u) {
    int c = c0 + ty + u * 8;
    dst[(size_t)c * R + r0 + tx] = t[tx][ty + u * 8];
  }
}

// V transpose per layer: qkv bf16 [MROWS][QKVS] V-part -> vt [B*H][64][1024]
__global__ __launch_bounds__(256) void vtrans_kernel(
    const unsigned short* __restrict__ qkv, unsigned short* __restrict__ vt) {
  __shared__ unsigned short t[32][33];
  int k0 = blockIdx.x * 32;   // key tile
  int d0 = blockIdx.y * 32;   // dim tile within head
  int bh = blockIdx.z;        // b*HEADS+h
  int b = bh / HEADS, h = bh % HEADS;
  int tx = threadIdx.x & 31, ty = threadIdx.x >> 5;
  const unsigned short* src =
      qkv + (size_t)(b * NTOK) * QKVS + 2 * INNER + h * DHEAD;
#pragma unroll
  for (int u = 0; u < 4; ++u)
    t[ty + u * 8][tx] = src[(size_t)(k0 + ty + u * 8) * QKVS + d0 + tx];
  __syncthreads();
  unsigned short* dst = vt + ((size_t)bh * DHEAD + d0) * NTOK + k0;
#pragma unroll
  for (int u = 0; u < 4; ++u)
    dst[(size_t)(ty + u * 8) * NTOK + tx] = t[tx][ty + u * 8];
}

// im2col -> bf16: x [B,C,H,W] -> A [MROWS, 192]
__global__ __launch_bounds__(256) void im2col_kernel(
    const float* __restrict__ x, unsigned short* __restrict__ A) {
  int idx = blockIdx.x * 256 + threadIdx.x;
  if (idx >= MROWS * KPATCH) return;
  int m = idx / KPATCH, k = idx % KPATCH;
  int b = m / NTOK, n = m % NTOK;
  int ph = n / 32, pw = n % 32;
  int c = k / 64, r = k % 64;
  int py = r / 8, px = r % 8;
  A[idx] =
      f2b(x[((size_t)(b * CIN + c) * HIMG + ph * 8 + py) * WIMG + pw * 8 + px]);
}

// ---------------------------------------------------------------------------
// bf16 MFMA GEMM: C[M,N] = A[M,K] @ Bt[N,K]^T, fp32 accumulate.
// Register-prefetch double-buffer K-loop: K-tile t+1 loaded into VGPRs with
// plain global loads (these cross s_barrier without a vmcnt(0) drain, unlike
// global_load_lds), ds_write at top of iter t+1. N-tile fixed 128; MT=128
// (256 thr, 4 waves, 2x2 quadrants) or MT=64 (128 thr, 2 waves side by side
// in N) for N=768 GEMMs -> 768 blocks = 3/CU, no tail round.
// 1-D grid, XCD swizzle: bid&7 = XCD, n-tile fastest within XCD (A row-tile
// fetched once per XCD L2).
// EPI: 0 none; 2 +bias+res(fp32); 3 +bias,GELU; 4 +bias+pos_emb;
//      5 qkv (scale Q columns by QSCALE). OB: bf16 out.
template <int EPI, int OB, int MT>
__global__ __launch_bounds__(MT == 128 ? 256 : 128) void mfma_gemm_kernel(
    const unsigned short* __restrict__ Ag, const unsigned short* __restrict__ Bt,
    const float* __restrict__ bias, const float* __restrict__ res,
    void* __restrict__ Cg, int Mdim, int Ndim, int Kdim) {
  constexpr int NTT = 128;
  constexpr int NW = (MT == 128) ? 4 : 2;   // waves per block
  constexpr int BRW = NTT / NW;             // B rows staged per wave (32 or 64)
  constexpr int NA = 2;                     // A int4 loads/thread
  constexpr int NB = BRW / 16;              // B int4 loads/thread (2 or 4)
  __shared__ __align__(16) unsigned short Asm[MT * 32];
  __shared__ __align__(16) unsigned short Bsm[NTT * 32];
  int tid = threadIdx.x;
  int lane = tid & 63, wv = tid >> 6;

  // XCD-aware swizzle (1-D grid of (M/MT)*(N/128) blocks)
  int Nt = Ndim / NTT;
  int mchunk = (Mdim / MT) >> 3;
  int bid = blockIdx.x;
  int xcd = bid & 7;
  int j = bid >> 3;
  int m0 = (xcd * mchunk + j / Nt) * MT;
  int n0 = (j % Nt) * NTT;

  v4f acc[4][4] = {};
  int srow = lane >> 2, schunk = (lane & 3) * 8;

  const unsigned short* Aw =
      Ag + (size_t)(m0 + 32 * wv + srow) * Kdim + schunk;
  const unsigned short* Bw =
      Bt + (size_t)(n0 + BRW * wv + srow) * Kdim + schunk;
  unsigned short* Asw = Asm + (32 * wv + srow) * 32 + schunk;
  unsigned short* Bsw = Bsm + (BRW * wv + srow) * 32 + schunk;

  int quad = lane >> 4, lr = lane & 15;
  int fr0 = (MT == 128) ? ((wv >> 1) * 64) : 0;
  int fc0 = (MT == 128) ? ((wv & 1) * 64) : (wv * 64);
  const unsigned short* Afr = Asm + (fr0 + lr) * 32 + quad * 8;
  const unsigned short* Bfr = Bsm + (fc0 + lr) * 32 + quad * 8;

  int4 pa[NA], pb[NB];
#pragma unroll
  for (int u = 0; u < NA; ++u)
    pa[u] = *(const int4*)(Aw + (size_t)(16 * u) * Kdim);
#pragma unroll
  for (int u = 0; u < NB; ++u)
    pb[u] = *(const int4*)(Bw + (size_t)(16 * u) * Kdim);

  for (int k0 = 0; k0 < Kdim; k0 += 32) {
    __syncthreads();  // all waves done reading LDS from prev iter
#pragma unroll
    for (int u = 0; u < NA; ++u) *(int4*)(Asw + 16 * u * 32) = pa[u];
#pragma unroll
    for (int u = 0; u < NB; ++u) *(int4*)(Bsw + 16 * u * 32) = pb[u];
    if (k0 + 32 < Kdim) {  // prefetch next K-tile; stays in flight past barrier
#pragma unroll
      for (int u = 0; u < NA; ++u)
        pa[u] = *(const int4*)(Aw + k0 + 32 + (size_t)(16 * u) * Kdim);
#pragma unroll
      for (int u = 0; u < NB; ++u)
        pb[u] = *(const int4*)(Bw + k0 + 32 + (size_t)(16 * u) * Kdim);
    }
    __syncthreads();  // staged tile visible
    short8 af[4], bf[4];
#pragma unroll
    for (int i = 0; i < 4; ++i) af[i] = *(const short8*)(Afr + i * 16 * 32);
#pragma unroll
    for (int i = 0; i < 4; ++i) bf[i] = *(const short8*)(Bfr + i * 16 * 32);
#pragma unroll
    for (int i = 0; i < 4; ++i)
#pragma unroll
      for (int n = 0; n < 4; ++n)
        acc[i][n] = __builtin_amdgcn_mfma_f32_16x16x32_bf16(af[i], bf[n],
                                                            acc[i][n], 0, 0, 0);
  }

  // epilogue: C/D layout col=lane&15, row=quad*4+reg
  float* Cf = (float*)Cg;
  unsigned short* Cb = (unsigned short*)Cg;
#pragma unroll
  for (int i = 0; i < 4; ++i) {
#pragma unroll
    for (int n = 0; n < 4; ++n) {
      int ncol = n0 + fc0 + 16 * n + lr;
#pragma unroll
      for (int reg = 0; reg < 4; ++reg) {
        int mrow = m0 + fr0 + 16 * i + quad * 4 + reg;
        float v = acc[i][n][reg];
        if (EPI == 2 || EPI == 3 || EPI == 4) v += bias[ncol];
        if (EPI == 2) v += res[(size_t)mrow * Ndim + ncol];
        if (EPI == 3) v = 0.5f * v * (1.0f + erff(v * 0.70710678118654752f));
        if (EPI == 4) v += res[(size_t)(mrow % NTOK) * Ndim + ncol];
        if (EPI == 5 && ncol < INNER) v *= QSCALE;
        if (OB)
          Cb[(size_t)mrow * Ndim + ncol] = f2b(v);
        else
          Cf[(size_t)mrow * Ndim + ncol] = v;
      }
    }
  }
}

// ---------------------------------------------------------------------------
// LayerNorm over last dim (768), fp32 in -> bf16 out. One block per row.
__global__ __launch_bounds__(256) void ln_kernel(
    const float* __restrict__ x, const float* __restrict__ w,
    const float* __restrict__ b, unsigned short* __restrict__ y) {
  int row = blockIdx.x;
  const float* xr = x + (size_t)row * DMODEL;
  unsigned short* yr = y + (size_t)row * DMODEL;
  int tid = threadIdx.x;
  float v0 = xr[tid], v1 = xr[tid + 256], v2 = xr[tid + 512];
  float s = v0 + v1 + v2;
  __shared__ float red[4];
#pragma unroll
  for (int off = 32; off >= 1; off >>= 1) s += __shfl_xor(s, off, 64);
  if ((tid & 63) == 0) red[tid >> 6] = s;
  __syncthreads();
  float mean = (red[0] + red[1] + red[2] + red[3]) * (1.0f / DMODEL);
  float d0 = v0 - mean, d1 = v1 - mean, d2 = v2 - mean;
  float sq = d0 * d0 + d1 * d1 + d2 * d2;
  __syncthreads();
#pragma unroll
  for (int off = 32; off >= 1; off >>= 1) sq += __shfl_xor(sq, off, 64);
  if ((tid & 63) == 0) red[tid >> 6] = sq;
  __syncthreads();
  float var = (red[0] + red[1] + red[2] + red[3]) * (1.0f / DMODEL);
  float rs = rsqrtf(var + LNEPS);
  yr[tid] = f2b(d0 * rs * w[tid] + b[tid]);
  yr[tid + 256] = f2b(d1 * rs * w[tid + 256] + b[tid + 256]);
  yr[tid + 512] = f2b(d2 * rs * w[tid + 512] + b[tid + 512]);
}

// ---------------------------------------------------------------------------
// MFMA flash attention. Block = (128 q-rows, head, batch); 4 waves x 32 q.
// S^T = K @ Q^T (C/D col = q), online softmax via in-wave shuffles, P packed
// bf16 into per-wave LDS in A-fragment layout, O = P @ V with pre-transposed
// V (vtg). Q pre-scaled by QSCALE in qkv GEMM -> softmax uses native exp2.
__global__ __launch_bounds__(256) void attn_kernel(
    const unsigned short* __restrict__ qkv,
    const unsigned short* __restrict__ vtg, unsigned short* __restrict__ o) {
  __shared__ __align__(16) unsigned short Ks[64 * PSTR];
  __shared__ __align__(16) unsigned short Vs[64 * PSTR];
  __shared__ __align__(16) unsigned short Pl[4][32 * PSTR];
  int tid = threadIdx.x;
  int lane = tid & 63, wv = tid >> 6;
  int quad = lane >> 4, lr = lane & 15;
  int q0 = blockIdx.x * 128, hh = blockIdx.y, bb = blockIdx.z;

  const unsigned short* qg =
      qkv + (size_t)(bb * NTOK + q0 + wv * 32) * QKVS + hh * DHEAD;
  const unsigned short* kg =
      qkv + (size_t)(bb * NTOK) * QKVS + INNER + hh * DHEAD;
  const unsigned short* vg = vtg + (size_t)(bb * HEADS + hh) * DHEAD * NTOK;
  unsigned short* Pw = Pl[wv];

  int srow = lane >> 3, soff = (lane & 7) * 8;

#pragma unroll
  for (int p = 0; p < 4; ++p) {
    int r = p * 8 + srow;
    *(int4*)(Pw + r * PSTR + soff) =
        *(const int4*)(qg + (size_t)r * QKVS + soff);
  }
  short8 qf[2][2];
#pragma unroll
  for (int n = 0; n < 2; ++n)
#pragma unroll
    for (int s = 0; s < 2; ++s)
      qf[n][s] =
          *(const short8*)(Pw + (n * 16 + lr) * PSTR + s * 32 + quad * 8);

  v4f oac[2][4] = {};
  float m_i[2] = {-1e30f, -1e30f};
  float l_i[2] = {0.f, 0.f};

  for (int t = 0; t < NTOK / 64; ++t) {
    __syncthreads();
#pragma unroll
    for (int p = 0; p < 2; ++p) {
      int r = wv * 16 + p * 8 + srow;
      *(int4*)(Ks + r * PSTR + soff) =
          *(const int4*)(kg + (size_t)(t * 64 + r) * QKVS + soff);
      *(int4*)(Vs + r * PSTR + soff) =
          *(const int4*)(vg + (size_t)r * NTOK + t * 64 + soff);
    }
    __syncthreads();

    v4f sac[4][2] = {};
#pragma unroll
    for (int s = 0; s < 2; ++s) {
      short8 kf[4];
#pragma unroll
      for (int mt = 0; mt < 4; ++mt)
        kf[mt] =
            *(const short8*)(Ks + (mt * 16 + lr) * PSTR + s * 32 + quad * 8);
#pragma unroll
      for (int mt = 0; mt < 4; ++mt)
#pragma unroll
        for (int n = 0; n < 2; ++n)
          sac[mt][n] = __builtin_amdgcn_mfma_f32_16x16x32_bf16(
              kf[mt], qf[n][s], sac[mt][n], 0, 0, 0);
    }

#pragma unroll
    for (int n = 0; n < 2; ++n) {
      float mx = -1e30f;
#pragma unroll
      for (int mt = 0; mt < 4; ++mt)
#pragma unroll
        for (int r = 0; r < 4; ++r) mx = fmaxf(mx, sac[mt][n][r]);
      mx = fmaxf(mx, __shfl_xor(mx, 16, 64));
      mx = fmaxf(mx, __shfl_xor(mx, 32, 64));
      float mnew = fmaxf(m_i[n], mx);
      float alpha = __builtin_amdgcn_exp2f(m_i[n] - mnew);
      m_i[n] = mnew;
      float sum = 0.f;
#pragma unroll
      for (int mt = 0; mt < 4; ++mt) {
#pragma unroll
        for (int r = 0; r < 4; ++r) {
          float p = __builtin_amdgcn_exp2f(sac[mt][n][r] - mnew);
          sac[mt][n][r] = p;
          sum += p;
        }
        *(uint2*)(Pw + (n * 16 + lr) * PSTR + mt * 16 + quad * 4) =
            make_uint2(pkrh(sac[mt][n][0], sac[mt][n][1]),
                       pkrh(sac[mt][n][2], sac[mt][n][3]));
      }
      sum += __shfl_xor(sum, 16, 64);
      sum += __shfl_xor(sum, 32, 64);
      l_i[n] = l_i[n] * alpha + sum;
#pragma unroll
      for (int r = 0; r < 4; ++r) {
        float ao = __shfl(alpha, quad * 4 + r, 64);
#pragma unroll
        for (int j = 0; j < 4; ++j) oac[n][j][r] *= ao;
      }
    }

#pragma unroll
    for (int s = 0; s < 2; ++s) {
      short8 pf[2], vf[4];
#pragma unroll
      for (int i = 0; i < 2; ++i)
        pf[i] =
            *(const short8*)(Pw + (i * 16 + lr) * PSTR + s * 32 + quad * 8);
#pragma unroll
      for (int j = 0; j < 4; ++j)
        vf[j] =
            *(const short8*)(Vs + (j * 16 + lr) * PSTR + s * 32 + quad * 8);
#pragma unroll
      for (int i = 0; i < 2; ++i)
#pragma unroll
        for (int j = 0; j < 4; ++j)
          oac[i][j] = __builtin_amdgcn_mfma_f32_16x16x32_bf16(
              pf[i], vf[j], oac[i][j], 0, 0, 0);
    }
  }

  unsigned short* ob =
      o + (size_t)(bb * NTOK + q0 + wv * 32) * INNER + hh * DHEAD;
#pragma unroll
  for (int i = 0; i < 2; ++i) {
    float inv = 1.0f / l_i[i];
#pragma unroll
    for (int r = 0; r < 4; ++r) {
      float il = __shfl(inv, quad * 4 + r, 64);
      int row = i * 16 + quad * 4 + r;
#pragma unroll
      for (int j = 0; j < 4; ++j)
        ob[(size_t)row * INNER + 16 * j + lr] = f2b(oac[i][j][r] * il);
    }
  }
}

// ---------------------------------------------------------------------------
extern "C" void kernel_launch(void* const* d_in, const int* in_sizes, int n_in,
                              void* d_out, int out_size, void* d_ws,
                              size_t ws_size, hipStream_t stream) {
  const float* x      = (const float*)d_in[0];
  const float* w_conv = (const float*)d_in[1];
  const float* b_conv = (const float*)d_in[2];
  const float* pos    = (const float*)d_in[3];
  const float* ln1w   = (const float*)d_in[4];
  const float* ln1b   = (const float*)d_in[5];
  const float* qkvw   = (const float*)d_in[6];
  const float* outw   = (const float*)d_in[7];
  const float* outb   = (const float*)d_in[8];
  const float* ln2w   = (const float*)d_in[9];
  const float* ln2b   = (const float*)d_in[10];
  const float* w1     = (const float*)d_in[11];
  const float* b1     = (const float*)d_in[12];
  const float* w2     = (const float*)d_in[13];
  const float* b2     = (const float*)d_in[14];

  char* ws = (char*)d_ws;
  float* h            = (float*)(ws + 0);                 // 25,165,824 B
  unsigned short* big = (unsigned short*)(ws + 25165824); // 50,331,648 B
  unsigned short* y   = (unsigned short*)(ws + 75497472); // 12,582,912 B
  unsigned short* wq  = (unsigned short*)(ws + 88080384); //  3,538,944 B
  unsigned short* wo  = (unsigned short*)(ws + 91619328); //  1,179,648 B
  unsigned short* w1t = (unsigned short*)(ws + 92798976); //  4,718,592 B
  unsigned short* w2t = (unsigned short*)(ws + 97517568); //  4,718,592 B
  unsigned short* wc  = (unsigned short*)(ws + 102236160);//    294,912 B
  unsigned short* vt  = (unsigned short*)(ws + 102531072);// 12,582,912 B
  float* outp = (float*)d_out;

  dim3 blk(256);
  dim3 blk128(128);

  cast_kernel<<<dim3((DMODEL * KPATCH + 255) / 256), blk, 0, stream>>>(
      w_conv, wc, DMODEL * KPATCH);
  im2col_kernel<<<dim3((MROWS * KPATCH + 255) / 256), blk, 0, stream>>>(x, big);
  // patch embed: [8192,192] @ wc[768,192]^T + b_conv + pos -> h fp32
  mfma_gemm_kernel<4, 0, 64>
      <<<dim3((MROWS / 64) * (DMODEL / 128)), blk128, 0, stream>>>(
          big, wc, b_conv, pos, h, MROWS, DMODEL, KPATCH);

  for (int l = 0; l < DEPTH; ++l) {
    transpose_cast_kernel<<<dim3(QKVS / 32, DMODEL / 32), blk, 0, stream>>>(
        qkvw + (size_t)l * DMODEL * QKVS, wq, DMODEL, QKVS);
    ln_kernel<<<dim3(MROWS), blk, 0, stream>>>(h, ln1w + l * DMODEL,
                                               ln1b + l * DMODEL, y);
    mfma_gemm_kernel<5, 1, 128>
        <<<dim3((MROWS / 128) * (QKVS / 128)), blk, 0, stream>>>(
            y, wq, nullptr, nullptr, big, MROWS, QKVS, DMODEL);
    vtrans_kernel<<<dim3(NTOK / 32, DHEAD / 32, BATCH * HEADS), blk, 0,
                    stream>>>(big, vt);
    attn_kernel<<<dim3(NTOK / 128, HEADS, BATCH), blk, 0, stream>>>(big, vt, y);
    transpose_cast_kernel<<<dim3(DMODEL / 32, INNER / 32), blk, 0, stream>>>(
        outw + (size_t)l * INNER * DMODEL, wo, INNER, DMODEL);
    mfma_gemm_kernel<2, 0, 64>
        <<<dim3((MROWS / 64) * (DMODEL / 128)), blk128, 0, stream>>>(
            y, wo, outb + l * DMODEL, h, h, MROWS, DMODEL, INNER);
    ln_kernel<<<dim3(MROWS), blk, 0, stream>>>(h, ln2w + l * DMODEL,
                                               ln2b + l * DMODEL, y);
    transpose_cast_kernel<<<dim3(MLPDIM / 32, DMODEL / 32), blk, 0, stream>>>(
        w1 + (size_t)l * DMODEL * MLPDIM, w1t, DMODEL, MLPDIM);
    mfma_gemm_kernel<3, 1, 128>
        <<<dim3((MROWS / 128) * (MLPDIM / 128)), blk, 0, stream>>>(
            y, w1t, b1 + l * MLPDIM, nullptr, big, MROWS, MLPDIM, DMODEL);
    transpose_cast_kernel<<<dim3(DMODEL / 32, MLPDIM / 32), blk, 0, stream>>>(
        w2 + (size_t)l * MLPDIM * DMODEL, w2t, MLPDIM, DMODEL);
    float* dst = (l == DEPTH - 1) ? outp : h;
    mfma_gemm_kernel<2, 0, 64>
        <<<dim3((MROWS / 64) * (DMODEL / 128)), blk128, 0, stream>>>(
            big, w2t, b2 + l * DMODEL, h, dst, MROWS, DMODEL, MLPDIM);
  }
}

// Round 6
// 2624.618 us; speedup vs baseline: 2.2446x; 2.2446x over previous
//
#include <hip/hip_runtime.h>
#include <math.h>

// Problem constants (ViT-Base-ish)
#define BATCH 8
#define CIN 3
#define HIMG 256
#define WIMG 256
#define PATCH 8
#define DMODEL 768
#define DEPTH 8
#define HEADS 12
#define DHEAD 64
#define MLPDIM 3072
#define NTOK 1024              // (256/8)^2
#define INNER 768              // HEADS*DHEAD
#define MROWS (BATCH * NTOK)   // 8192
#define QKVS (3 * INNER)       // 2304
#define KPATCH (CIN * PATCH * PATCH)  // 192
#define LNEPS 1e-5f
#define PSTR 72                // attn LDS row stride (16B-aligned, conflict-safe)
// 0.125 (dh^-0.5) * log2(e): folded into Q so softmax uses exp2 (v_exp_f32)
#define QSCALE 0.18033688011112042f

typedef __attribute__((ext_vector_type(8))) short short8;  // 8 bf16 (4 VGPRs)
typedef __attribute__((ext_vector_type(4))) float v4f;     // MFMA accumulator

__device__ __forceinline__ float b2f(unsigned short u) {
  union { unsigned int i; float f; } x;
  x.i = (unsigned int)u << 16;
  return x.f;
}
__device__ __forceinline__ unsigned short f2b(float f) {
  union { float f; unsigned int i; } x;
  x.f = f;
  unsigned int r = x.i + 0x7FFFu + ((x.i >> 16) & 1u);  // RNE
  return (unsigned short)(r >> 16);
}
// pack 2 fp32 -> 2 bf16 in one u32, round-half-up (cheap: 4 VALU)
__device__ __forceinline__ unsigned int pkrh(float a, float b) {
  union { float f; unsigned int u; } x, y;
  x.f = a; y.f = b;
  return ((x.u + 0x8000u) >> 16) | ((y.u + 0x8000u) & 0xFFFF0000u);
}

// async 16B/lane global->LDS (wave-uniform LDS base + lane*16B)
#define GLL(gp, lp)                                                     \
  __builtin_amdgcn_global_load_lds(                                     \
      (const __attribute__((address_space(1))) void*)(gp),              \
      (__attribute__((address_space(3))) void*)(lp), 16, 0, 0)

// ---------------------------------------------------------------------------
// elementwise fp32 -> bf16 cast (w_conv: [768,192] already [N,K])
__global__ __launch_bounds__(256) void cast_kernel(
    const float* __restrict__ src, unsigned short* __restrict__ dst, int n) {
  int i = blockIdx.x * 256 + threadIdx.x;
  if (i < n) dst[i] = f2b(src[i]);
}

// transpose-cast: src fp32 [R,C] -> dst bf16 [C,R]. R,C multiples of 32.
__global__ __launch_bounds__(256) void transpose_cast_kernel(
    const float* __restrict__ src, unsigned short* __restrict__ dst, int R,
    int C) {
  __shared__ unsigned short t[32][33];
  int c0 = blockIdx.x * 32, r0 = blockIdx.y * 32;
  int tx = threadIdx.x & 31, ty = threadIdx.x >> 5;  // 32 x 8
#pragma unroll
  for (int u = 0; u < 4; ++u) {
    int r = r0 + ty + u * 8;
    t[ty + u * 8][tx] = f2b(src[(size_t)r * C + c0 + tx]);
  }
  __syncthreads();
#pragma unroll
  for (int u = 0; u < 4; ++u) {
    int c = c0 + ty + u * 8;
    dst[(size_t)c * R + r0 + tx] = t[tx][ty + u * 8];
  }
}

// V transpose per layer: qkv bf16 [MROWS][QKVS] V-part -> vt [B*H][64][1024]
__global__ __launch_bounds__(256) void vtrans_kernel(
    const unsigned short* __restrict__ qkv, unsigned short* __restrict__ vt) {
  __shared__ unsigned short t[32][33];
  int k0 = blockIdx.x * 32;   // key tile
  int d0 = blockIdx.y * 32;   // dim tile within head
  int bh = blockIdx.z;        // b*HEADS+h
  int b = bh / HEADS, h = bh % HEADS;
  int tx = threadIdx.x & 31, ty = threadIdx.x >> 5;
  const unsigned short* src =
      qkv + (size_t)(b * NTOK) * QKVS + 2 * INNER + h * DHEAD;
#pragma unroll
  for (int u = 0; u < 4; ++u)
    t[ty + u * 8][tx] = src[(size_t)(k0 + ty + u * 8) * QKVS + d0 + tx];
  __syncthreads();
  unsigned short* dst = vt + ((size_t)bh * DHEAD + d0) * NTOK + k0;
#pragma unroll
  for (int u = 0; u < 4; ++u)
    dst[(size_t)(ty + u * 8) * NTOK + tx] = t[tx][ty + u * 8];
}

// im2col -> bf16: x [B,C,H,W] -> A [MROWS, 192]
__global__ __launch_bounds__(256) void im2col_kernel(
    const float* __restrict__ x, unsigned short* __restrict__ A) {
  int idx = blockIdx.x * 256 + threadIdx.x;
  if (idx >= MROWS * KPATCH) return;
  int m = idx / KPATCH, k = idx % KPATCH;
  int b = m / NTOK, n = m % NTOK;
  int ph = n / 32, pw = n % 32;
  int c = k / 64, r = k % 64;
  int py = r / 8, px = r % 8;
  A[idx] =
      f2b(x[((size_t)(b * CIN + c) * HIMG + ph * 8 + py) * WIMG + pw * 8 + px]);
}

// ---------------------------------------------------------------------------
// bf16 MFMA GEMM: C[M,N] = A[M,K] @ Bt[N,K]^T, fp32 accumulate.
// Round-4-proven structure: global_load_lds (width 16) staging, BK=32,
// 2-barrier K-loop, 256 threads / 4 waves. N-tile fixed 128.
// MT=128: 2x2 quadrants of 64x64/wave (acc 4x4).
// MT=64 : 2x2 quadrants of 32x64/wave (acc 2x4) -> for N=768 GEMMs the grid
//         becomes 768 blocks = 3 blocks/CU (12 waves/CU), no tail round.
// 1-D grid, XCD swizzle: bid&7 = XCD, n fastest within XCD (proven: cuts
// FETCH 169->60 MB on ffn2).
// EPI: 0 none; 2 +bias+res(fp32); 3 +bias,GELU; 4 +bias+pos_emb;
//      5 qkv (scale Q columns by QSCALE). OB: bf16 out.
template <int EPI, int OB, int MT>
__global__ __launch_bounds__(256) void mfma_gemm_kernel(
    const unsigned short* __restrict__ Ag, const unsigned short* __restrict__ Bt,
    const float* __restrict__ bias, const float* __restrict__ res,
    void* __restrict__ Cg, int Mdim, int Ndim, int Kdim) {
  constexpr int MI = MT / 32;               // m fragment tiles per wave (4|2)
  constexpr int RA = MT / 4;                // A rows staged per wave (32|16)
  constexpr int NGA = RA / 16;              // A GLL chunks per wave (2|1)
  __shared__ __align__(16) unsigned short Asm[MT * 32];
  __shared__ __align__(16) unsigned short Bsm[128 * 32];
  int tid = threadIdx.x;
  int lane = tid & 63, wv = tid >> 6;

  // XCD-aware swizzle (1-D grid of (M/MT)*(N/128) blocks)
  int Nt = Ndim / 128;
  int mchunk = (Mdim / MT) >> 3;
  int bid = blockIdx.x;
  int xcd = bid & 7;
  int j = bid >> 3;
  int m0 = (xcd * mchunk + j / Nt) * MT;
  int n0 = (j % Nt) * 128;

  v4f acc[MI][4] = {};
  int srow = lane >> 2, schunk = (lane & 3) * 8;

  const unsigned short* Aw = Ag + (size_t)(m0 + RA * wv + srow) * Kdim + schunk;
  const unsigned short* Bw = Bt + (size_t)(n0 + 32 * wv + srow) * Kdim + schunk;
  unsigned short* As0 = Asm + (RA * wv) * 32;
  unsigned short* Bs0 = Bsm + (32 * wv) * 32;

  int quad = lane >> 4, lr = lane & 15;
  int fr0 = (wv >> 1) * (MI * 16);
  int fc0 = (wv & 1) * 64;
  const unsigned short* Afr = Asm + (fr0 + lr) * 32 + quad * 8;
  const unsigned short* Bfr = Bsm + (fc0 + lr) * 32 + quad * 8;

  for (int k0 = 0; k0 < Kdim; k0 += 32) {
    GLL(Aw + k0, As0);
    if (NGA == 2) GLL(Aw + k0 + (size_t)16 * Kdim, As0 + 16 * 32);
    GLL(Bw + k0, Bs0);
    GLL(Bw + k0 + (size_t)16 * Kdim, Bs0 + 16 * 32);
    __syncthreads();
    short8 af[MI], bf[4];
#pragma unroll
    for (int i = 0; i < MI; ++i) af[i] = *(const short8*)(Afr + i * 16 * 32);
#pragma unroll
    for (int n = 0; n < 4; ++n) bf[n] = *(const short8*)(Bfr + n * 16 * 32);
#pragma unroll
    for (int i = 0; i < MI; ++i)
#pragma unroll
      for (int n = 0; n < 4; ++n)
        acc[i][n] = __builtin_amdgcn_mfma_f32_16x16x32_bf16(af[i], bf[n],
                                                            acc[i][n], 0, 0, 0);
    __syncthreads();
  }

  // epilogue: C/D layout col=lane&15, row=quad*4+reg
  float* Cf = (float*)Cg;
  unsigned short* Cb = (unsigned short*)Cg;
#pragma unroll
  for (int i = 0; i < MI; ++i) {
#pragma unroll
    for (int n = 0; n < 4; ++n) {
      int ncol = n0 + fc0 + 16 * n + lr;
#pragma unroll
      for (int reg = 0; reg < 4; ++reg) {
        int mrow = m0 + fr0 + 16 * i + quad * 4 + reg;
        float v = acc[i][n][reg];
        if (EPI == 2 || EPI == 3 || EPI == 4) v += bias[ncol];
        if (EPI == 2) v += res[(size_t)mrow * Ndim + ncol];
        if (EPI == 3) v = 0.5f * v * (1.0f + erff(v * 0.70710678118654752f));
        if (EPI == 4) v += res[(size_t)(mrow % NTOK) * Ndim + ncol];
        if (EPI == 5 && ncol < INNER) v *= QSCALE;
        if (OB)
          Cb[(size_t)mrow * Ndim + ncol] = f2b(v);
        else
          Cf[(size_t)mrow * Ndim + ncol] = v;
      }
    }
  }
}

// ---------------------------------------------------------------------------
// LayerNorm over last dim (768), fp32 in -> bf16 out. One block per row.
__global__ __launch_bounds__(256) void ln_kernel(
    const float* __restrict__ x, const float* __restrict__ w,
    const float* __restrict__ b, unsigned short* __restrict__ y) {
  int row = blockIdx.x;
  const float* xr = x + (size_t)row * DMODEL;
  unsigned short* yr = y + (size_t)row * DMODEL;
  int tid = threadIdx.x;
  float v0 = xr[tid], v1 = xr[tid + 256], v2 = xr[tid + 512];
  float s = v0 + v1 + v2;
  __shared__ float red[4];
#pragma unroll
  for (int off = 32; off >= 1; off >>= 1) s += __shfl_xor(s, off, 64);
  if ((tid & 63) == 0) red[tid >> 6] = s;
  __syncthreads();
  float mean = (red[0] + red[1] + red[2] + red[3]) * (1.0f / DMODEL);
  float d0 = v0 - mean, d1 = v1 - mean, d2 = v2 - mean;
  float sq = d0 * d0 + d1 * d1 + d2 * d2;
  __syncthreads();
#pragma unroll
  for (int off = 32; off >= 1; off >>= 1) sq += __shfl_xor(sq, off, 64);
  if ((tid & 63) == 0) red[tid >> 6] = sq;
  __syncthreads();
  float var = (red[0] + red[1] + red[2] + red[3]) * (1.0f / DMODEL);
  float rs = rsqrtf(var + LNEPS);
  yr[tid] = f2b(d0 * rs * w[tid] + b[tid]);
  yr[tid + 256] = f2b(d1 * rs * w[tid + 256] + b[tid + 256]);
  yr[tid + 512] = f2b(d2 * rs * w[tid + 512] + b[tid + 512]);
}

// ---------------------------------------------------------------------------
// MFMA flash attention. Block = (128 q-rows, head, batch); 4 waves x 32 q.
// S^T = K @ Q^T (C/D col = q), online softmax via in-wave shuffles, P packed
// bf16 into per-wave LDS in A-fragment layout, O = P @ V with pre-transposed
// V (vtg). Q pre-scaled by QSCALE in qkv GEMM -> softmax uses native exp2.
__global__ __launch_bounds__(256) void attn_kernel(
    const unsigned short* __restrict__ qkv,
    const unsigned short* __restrict__ vtg, unsigned short* __restrict__ o) {
  __shared__ __align__(16) unsigned short Ks[64 * PSTR];
  __shared__ __align__(16) unsigned short Vs[64 * PSTR];
  __shared__ __align__(16) unsigned short Pl[4][32 * PSTR];
  int tid = threadIdx.x;
  int lane = tid & 63, wv = tid >> 6;
  int quad = lane >> 4, lr = lane & 15;
  int q0 = blockIdx.x * 128, hh = blockIdx.y, bb = blockIdx.z;

  const unsigned short* qg =
      qkv + (size_t)(bb * NTOK + q0 + wv * 32) * QKVS + hh * DHEAD;
  const unsigned short* kg =
      qkv + (size_t)(bb * NTOK) * QKVS + INNER + hh * DHEAD;
  const unsigned short* vg = vtg + (size_t)(bb * HEADS + hh) * DHEAD * NTOK;
  unsigned short* Pw = Pl[wv];

  int srow = lane >> 3, soff = (lane & 7) * 8;

#pragma unroll
  for (int p = 0; p < 4; ++p) {
    int r = p * 8 + srow;
    *(int4*)(Pw + r * PSTR + soff) =
        *(const int4*)(qg + (size_t)r * QKVS + soff);
  }
  short8 qf[2][2];
#pragma unroll
  for (int n = 0; n < 2; ++n)
#pragma unroll
    for (int s = 0; s < 2; ++s)
      qf[n][s] =
          *(const short8*)(Pw + (n * 16 + lr) * PSTR + s * 32 + quad * 8);

  v4f oac[2][4] = {};
  float m_i[2] = {-1e30f, -1e30f};
  float l_i[2] = {0.f, 0.f};

  for (int t = 0; t < NTOK / 64; ++t) {
    __syncthreads();
#pragma unroll
    for (int p = 0; p < 2; ++p) {
      int r = wv * 16 + p * 8 + srow;
      *(int4*)(Ks + r * PSTR + soff) =
          *(const int4*)(kg + (size_t)(t * 64 + r) * QKVS + soff);
      *(int4*)(Vs + r * PSTR + soff) =
          *(const int4*)(vg + (size_t)r * NTOK + t * 64 + soff);
    }
    __syncthreads();

    v4f sac[4][2] = {};
#pragma unroll
    for (int s = 0; s < 2; ++s) {
      short8 kf[4];
#pragma unroll
      for (int mt = 0; mt < 4; ++mt)
        kf[mt] =
            *(const short8*)(Ks + (mt * 16 + lr) * PSTR + s * 32 + quad * 8);
#pragma unroll
      for (int mt = 0; mt < 4; ++mt)
#pragma unroll
        for (int n = 0; n < 2; ++n)
          sac[mt][n] = __builtin_amdgcn_mfma_f32_16x16x32_bf16(
              kf[mt], qf[n][s], sac[mt][n], 0, 0, 0);
    }

#pragma unroll
    for (int n = 0; n < 2; ++n) {
      float mx = -1e30f;
#pragma unroll
      for (int mt = 0; mt < 4; ++mt)
#pragma unroll
        for (int r = 0; r < 4; ++r) mx = fmaxf(mx, sac[mt][n][r]);
      mx = fmaxf(mx, __shfl_xor(mx, 16, 64));
      mx = fmaxf(mx, __shfl_xor(mx, 32, 64));
      float mnew = fmaxf(m_i[n], mx);
      float alpha = __builtin_amdgcn_exp2f(m_i[n] - mnew);
      m_i[n] = mnew;
      float sum = 0.f;
#pragma unroll
      for (int mt = 0; mt < 4; ++mt) {
#pragma unroll
        for (int r = 0; r < 4; ++r) {
          float p = __builtin_amdgcn_exp2f(sac[mt][n][r] - mnew);
          sac[mt][n][r] = p;
          sum += p;
        }
        *(uint2*)(Pw + (n * 16 + lr) * PSTR + mt * 16 + quad * 4) =
            make_uint2(pkrh(sac[mt][n][0], sac[mt][n][1]),
                       pkrh(sac[mt][n][2], sac[mt][n][3]));
      }
      sum += __shfl_xor(sum, 16, 64);
      sum += __shfl_xor(sum, 32, 64);
      l_i[n] = l_i[n] * alpha + sum;
#pragma unroll
      for (int r = 0; r < 4; ++r) {
        float ao = __shfl(alpha, quad * 4 + r, 64);
#pragma unroll
        for (int j = 0; j < 4; ++j) oac[n][j][r] *= ao;
      }
    }

#pragma unroll
    for (int s = 0; s < 2; ++s) {
      short8 pf[2], vf[4];
#pragma unroll
      for (int i = 0; i < 2; ++i)
        pf[i] =
            *(const short8*)(Pw + (i * 16 + lr) * PSTR + s * 32 + quad * 8);
#pragma unroll
      for (int j = 0; j < 4; ++j)
        vf[j] =
            *(const short8*)(Vs + (j * 16 + lr) * PSTR + s * 32 + quad * 8);
#pragma unroll
      for (int i = 0; i < 2; ++i)
#pragma unroll
        for (int j = 0; j < 4; ++j)
          oac[i][j] = __builtin_amdgcn_mfma_f32_16x16x32_bf16(
              pf[i], vf[j], oac[i][j], 0, 0, 0);
    }
  }

  unsigned short* ob =
      o + (size_t)(bb * NTOK + q0 + wv * 32) * INNER + hh * DHEAD;
#pragma unroll
  for (int i = 0; i < 2; ++i) {
    float inv = 1.0f / l_i[i];
#pragma unroll
    for (int r = 0; r < 4; ++r) {
      float il = __shfl(inv, quad * 4 + r, 64);
      int row = i * 16 + quad * 4 + r;
#pragma unroll
      for (int j = 0; j < 4; ++j)
        ob[(size_t)row * INNER + 16 * j + lr] = f2b(oac[i][j][r] * il);
    }
  }
}

// ---------------------------------------------------------------------------
extern "C" void kernel_launch(void* const* d_in, const int* in_sizes, int n_in,
                              void* d_out, int out_size, void* d_ws,
                              size_t ws_size, hipStream_t stream) {
  const float* x      = (const float*)d_in[0];
  const float* w_conv = (const float*)d_in[1];
  const float* b_conv = (const float*)d_in[2];
  const float* pos    = (const float*)d_in[3];
  const float* ln1w   = (const float*)d_in[4];
  const float* ln1b   = (const float*)d_in[5];
  const float* qkvw   = (const float*)d_in[6];
  const float* outw   = (const float*)d_in[7];
  const float* outb   = (const float*)d_in[8];
  const float* ln2w   = (const float*)d_in[9];
  const float* ln2b   = (const float*)d_in[10];
  const float* w1     = (const float*)d_in[11];
  const float* b1     = (const float*)d_in[12];
  const float* w2     = (const float*)d_in[13];
  const float* b2     = (const float*)d_in[14];

  char* ws = (char*)d_ws;
  float* h            = (float*)(ws + 0);                 // 25,165,824 B
  unsigned short* big = (unsigned short*)(ws + 25165824); // 50,331,648 B
  unsigned short* y   = (unsigned short*)(ws + 75497472); // 12,582,912 B
  unsigned short* wq  = (unsigned short*)(ws + 88080384); //  3,538,944 B
  unsigned short* wo  = (unsigned short*)(ws + 91619328); //  1,179,648 B
  unsigned short* w1t = (unsigned short*)(ws + 92798976); //  4,718,592 B
  unsigned short* w2t = (unsigned short*)(ws + 97517568); //  4,718,592 B
  unsigned short* wc  = (unsigned short*)(ws + 102236160);//    294,912 B
  unsigned short* vt  = (unsigned short*)(ws + 102531072);// 12,582,912 B
  float* outp = (float*)d_out;

  dim3 blk(256);

  cast_kernel<<<dim3((DMODEL * KPATCH + 255) / 256), blk, 0, stream>>>(
      w_conv, wc, DMODEL * KPATCH);
  im2col_kernel<<<dim3((MROWS * KPATCH + 255) / 256), blk, 0, stream>>>(x, big);
  // patch embed: [8192,192] @ wc[768,192]^T + b_conv + pos -> h fp32
  mfma_gemm_kernel<4, 0, 64>
      <<<dim3((MROWS / 64) * (DMODEL / 128)), blk, 0, stream>>>(
          big, wc, b_conv, pos, h, MROWS, DMODEL, KPATCH);

  for (int l = 0; l < DEPTH; ++l) {
    transpose_cast_kernel<<<dim3(QKVS / 32, DMODEL / 32), blk, 0, stream>>>(
        qkvw + (size_t)l * DMODEL * QKVS, wq, DMODEL, QKVS);
    ln_kernel<<<dim3(MROWS), blk, 0, stream>>>(h, ln1w + l * DMODEL,
                                               ln1b + l * DMODEL, y);
    mfma_gemm_kernel<5, 1, 128>
        <<<dim3((MROWS / 128) * (QKVS / 128)), blk, 0, stream>>>(
            y, wq, nullptr, nullptr, big, MROWS, QKVS, DMODEL);
    vtrans_kernel<<<dim3(NTOK / 32, DHEAD / 32, BATCH * HEADS), blk, 0,
                    stream>>>(big, vt);
    attn_kernel<<<dim3(NTOK / 128, HEADS, BATCH), blk, 0, stream>>>(big, vt, y);
    transpose_cast_kernel<<<dim3(DMODEL / 32, INNER / 32), blk, 0, stream>>>(
        outw + (size_t)l * INNER * DMODEL, wo, INNER, DMODEL);
    mfma_gemm_kernel<2, 0, 64>
        <<<dim3((MROWS / 64) * (DMODEL / 128)), blk, 0, stream>>>(
            y, wo, outb + l * DMODEL, h, h, MROWS, DMODEL, INNER);
    ln_kernel<<<dim3(MROWS), blk, 0, stream>>>(h, ln2w + l * DMODEL,
                                               ln2b + l * DMODEL, y);
    transpose_cast_kernel<<<dim3(MLPDIM / 32, DMODEL / 32), blk, 0, stream>>>(
        w1 + (size_t)l * DMODEL * MLPDIM, w1t, DMODEL, MLPDIM);
    mfma_gemm_kernel<3, 1, 128>
        <<<dim3((MROWS / 128) * (MLPDIM / 128)), blk, 0, stream>>>(
            y, w1t, b1 + l * MLPDIM, nullptr, big, MROWS, MLPDIM, DMODEL);
    transpose_cast_kernel<<<dim3(DMODEL / 32, MLPDIM / 32), blk, 0, stream>>>(
        w2 + (size_t)l * MLPDIM * DMODEL, w2t, MLPDIM, DMODEL);
    float* dst = (l == DEPTH - 1) ? outp : h;
    mfma_gemm_kernel<2, 0, 64>
        <<<dim3((MROWS / 64) * (DMODEL / 128)), blk, 0, stream>>>(
            big, w2t, b2 + l * DMODEL, h, dst, MROWS, DMODEL, MLPDIM);
  }
}

// Round 7
// 2543.060 us; speedup vs baseline: 2.3166x; 1.0321x over previous
//
#include <hip/hip_runtime.h>
#include <math.h>

// Problem constants (ViT-Base-ish)
#define BATCH 8
#define CIN 3
#define HIMG 256
#define WIMG 256
#define PATCH 8
#define DMODEL 768
#define DEPTH 8
#define HEADS 12
#define DHEAD 64
#define MLPDIM 3072
#define NTOK 1024              // (256/8)^2
#define INNER 768              // HEADS*DHEAD
#define MROWS (BATCH * NTOK)   // 8192
#define QKVS (3 * INNER)       // 2304
#define KPATCH (CIN * PATCH * PATCH)  // 192
#define LNEPS 1e-5f
#define PSTR 72                // attn LDS row stride (16B-aligned, conflict-safe)
// 0.125 (dh^-0.5) * log2(e): folded into Q so softmax uses exp2 (v_exp_f32)
#define QSCALE 0.18033688011112042f

typedef __attribute__((ext_vector_type(8))) short short8;  // 8 bf16 (4 VGPRs)
typedef __attribute__((ext_vector_type(4))) float v4f;     // MFMA accumulator

__device__ __forceinline__ float b2f(unsigned short u) {
  union { unsigned int i; float f; } x;
  x.i = (unsigned int)u << 16;
  return x.f;
}
__device__ __forceinline__ unsigned short f2b(float f) {
  union { float f; unsigned int i; } x;
  x.f = f;
  unsigned int r = x.i + 0x7FFFu + ((x.i >> 16) & 1u);  // RNE
  return (unsigned short)(r >> 16);
}
// pack 2 fp32 -> 2 bf16 in one u32, round-half-up (cheap: 4 VALU)
__device__ __forceinline__ unsigned int pkrh(float a, float b) {
  union { float f; unsigned int u; } x, y;
  x.f = a; y.f = b;
  return ((x.u + 0x8000u) >> 16) | ((y.u + 0x8000u) & 0xFFFF0000u);
}

// async 16B/lane global->LDS (wave-uniform LDS base + lane*16B)
#define GLL(gp, lp)                                                     \
  __builtin_amdgcn_global_load_lds(                                     \
      (const __attribute__((address_space(1))) void*)(gp),              \
      (__attribute__((address_space(3))) void*)(lp), 16, 0, 0)

// ---------------------------------------------------------------------------
// elementwise fp32 -> bf16 cast (w_conv: [768,192] already [N,K])
__global__ __launch_bounds__(256) void cast_kernel(
    const float* __restrict__ src, unsigned short* __restrict__ dst, int n) {
  int i = blockIdx.x * 256 + threadIdx.x;
  if (i < n) dst[i] = f2b(src[i]);
}

// transpose-cast: src fp32 [R,C] -> dst bf16 [C,R]. R,C multiples of 32.
// blockIdx.z selects a layer: both src and dst advance by R*C elements.
__global__ __launch_bounds__(256) void transpose_cast_kernel(
    const float* __restrict__ src, unsigned short* __restrict__ dst, int R,
    int C) {
  __shared__ unsigned short t[32][33];
  src += (size_t)blockIdx.z * R * C;
  dst += (size_t)blockIdx.z * R * C;
  int c0 = blockIdx.x * 32, r0 = blockIdx.y * 32;
  int tx = threadIdx.x & 31, ty = threadIdx.x >> 5;  // 32 x 8
#pragma unroll
  for (int u = 0; u < 4; ++u) {
    int r = r0 + ty + u * 8;
    t[ty + u * 8][tx] = f2b(src[(size_t)r * C + c0 + tx]);
  }
  __syncthreads();
#pragma unroll
  for (int u = 0; u < 4; ++u) {
    int c = c0 + ty + u * 8;
    dst[(size_t)c * R + r0 + tx] = t[tx][ty + u * 8];
  }
}

// V transpose per layer: qkv bf16 [MROWS][QKVS] V-part -> vt [B*H][64][1024]
__global__ __launch_bounds__(256) void vtrans_kernel(
    const unsigned short* __restrict__ qkv, unsigned short* __restrict__ vt) {
  __shared__ unsigned short t[32][33];
  int k0 = blockIdx.x * 32;   // key tile
  int d0 = blockIdx.y * 32;   // dim tile within head
  int bh = blockIdx.z;        // b*HEADS+h
  int b = bh / HEADS, h = bh % HEADS;
  int tx = threadIdx.x & 31, ty = threadIdx.x >> 5;
  const unsigned short* src =
      qkv + (size_t)(b * NTOK) * QKVS + 2 * INNER + h * DHEAD;
#pragma unroll
  for (int u = 0; u < 4; ++u)
    t[ty + u * 8][tx] = src[(size_t)(k0 + ty + u * 8) * QKVS + d0 + tx];
  __syncthreads();
  unsigned short* dst = vt + ((size_t)bh * DHEAD + d0) * NTOK + k0;
#pragma unroll
  for (int u = 0; u < 4; ++u)
    dst[(size_t)(ty + u * 8) * NTOK + tx] = t[tx][ty + u * 8];
}

// im2col -> bf16: x [B,C,H,W] -> A [MROWS, 192]
__global__ __launch_bounds__(256) void im2col_kernel(
    const float* __restrict__ x, unsigned short* __restrict__ A) {
  int idx = blockIdx.x * 256 + threadIdx.x;
  if (idx >= MROWS * KPATCH) return;
  int m = idx / KPATCH, k = idx % KPATCH;
  int b = m / NTOK, n = m % NTOK;
  int ph = n / 32, pw = n % 32;
  int c = k / 64, r = k % 64;
  int py = r / 8, px = r % 8;
  A[idx] =
      f2b(x[((size_t)(b * CIN + c) * HIMG + ph * 8 + py) * WIMG + pw * 8 + px]);
}

// ---------------------------------------------------------------------------
// bf16 MFMA GEMM: C[M,N] = A[M,K] @ Bt[N,K]^T, fp32 accumulate.
// Proven structure: global_load_lds (width 16) staging, BK=32, 2-barrier
// K-loop, 256 threads / 4 waves. N-tile fixed 128.
// MT=128: 2x2 quadrants of 64x64/wave (acc 4x4).
// MT=64 : 2x2 quadrants of 32x64/wave (acc 2x4) -> N=768 GEMMs get 768
//         blocks = 3 blocks/CU (12 waves/CU), no tail round.
// 1-D grid, XCD swizzle: bid&7 = XCD, n fastest within XCD (proven: cuts
// FETCH 169->60 MB on ffn2).
// EPI: 0 none; 2 +bias+res(fp32); 3 +bias, fast exact-GELU (tanh form via
//      hw exp2/rcp; max dev ~3e-4); 4 +bias+pos_emb; 5 qkv (Q cols * QSCALE).
// OB: bf16 out.
template <int EPI, int OB, int MT>
__global__ __launch_bounds__(256) void mfma_gemm_kernel(
    const unsigned short* __restrict__ Ag, const unsigned short* __restrict__ Bt,
    const float* __restrict__ bias, const float* __restrict__ res,
    void* __restrict__ Cg, int Mdim, int Ndim, int Kdim) {
  constexpr int MI = MT / 32;               // m fragment tiles per wave (4|2)
  constexpr int RA = MT / 4;                // A rows staged per wave (32|16)
  constexpr int NGA = RA / 16;              // A GLL chunks per wave (2|1)
  __shared__ __align__(16) unsigned short Asm[MT * 32];
  __shared__ __align__(16) unsigned short Bsm[128 * 32];
  int tid = threadIdx.x;
  int lane = tid & 63, wv = tid >> 6;

  // XCD-aware swizzle (1-D grid of (M/MT)*(N/128) blocks)
  int Nt = Ndim / 128;
  int mchunk = (Mdim / MT) >> 3;
  int bid = blockIdx.x;
  int xcd = bid & 7;
  int j = bid >> 3;
  int m0 = (xcd * mchunk + j / Nt) * MT;
  int n0 = (j % Nt) * 128;

  v4f acc[MI][4] = {};
  int srow = lane >> 2, schunk = (lane & 3) * 8;

  const unsigned short* Aw = Ag + (size_t)(m0 + RA * wv + srow) * Kdim + schunk;
  const unsigned short* Bw = Bt + (size_t)(n0 + 32 * wv + srow) * Kdim + schunk;
  unsigned short* As0 = Asm + (RA * wv) * 32;
  unsigned short* Bs0 = Bsm + (32 * wv) * 32;

  int quad = lane >> 4, lr = lane & 15;
  int fr0 = (wv >> 1) * (MI * 16);
  int fc0 = (wv & 1) * 64;
  const unsigned short* Afr = Asm + (fr0 + lr) * 32 + quad * 8;
  const unsigned short* Bfr = Bsm + (fc0 + lr) * 32 + quad * 8;

  for (int k0 = 0; k0 < Kdim; k0 += 32) {
    GLL(Aw + k0, As0);
    if (NGA == 2) GLL(Aw + k0 + (size_t)16 * Kdim, As0 + 16 * 32);
    GLL(Bw + k0, Bs0);
    GLL(Bw + k0 + (size_t)16 * Kdim, Bs0 + 16 * 32);
    __syncthreads();
    short8 af[MI], bf[4];
#pragma unroll
    for (int i = 0; i < MI; ++i) af[i] = *(const short8*)(Afr + i * 16 * 32);
#pragma unroll
    for (int n = 0; n < 4; ++n) bf[n] = *(const short8*)(Bfr + n * 16 * 32);
#pragma unroll
    for (int i = 0; i < MI; ++i)
#pragma unroll
      for (int n = 0; n < 4; ++n)
        acc[i][n] = __builtin_amdgcn_mfma_f32_16x16x32_bf16(af[i], bf[n],
                                                            acc[i][n], 0, 0, 0);
    __syncthreads();
  }

  // epilogue: C/D layout col=lane&15, row=quad*4+reg
  float* Cf = (float*)Cg;
  unsigned short* Cb = (unsigned short*)Cg;
#pragma unroll
  for (int i = 0; i < MI; ++i) {
#pragma unroll
    for (int n = 0; n < 4; ++n) {
      int ncol = n0 + fc0 + 16 * n + lr;
#pragma unroll
      for (int reg = 0; reg < 4; ++reg) {
        int mrow = m0 + fr0 + 16 * i + quad * 4 + reg;
        float v = acc[i][n][reg];
        if (EPI == 2 || EPI == 3 || EPI == 4) v += bias[ncol];
        if (EPI == 2) v += res[(size_t)mrow * Ndim + ncol];
        if (EPI == 3) {
          // gelu(x) ~= x * sigmoid(2*0.79788456*(x + 0.044715 x^3)); hw exp2
          float u = v * (0.7978845608028654f + 0.035677408136300125f * v * v);
          float a = fminf(fmaxf(u * 2.8853900817779268f, -60.f), 60.f);
          float E = __builtin_amdgcn_exp2f(a);
          v = v * E * __builtin_amdgcn_rcpf(E + 1.0f);
        }
        if (EPI == 4) v += res[(size_t)(mrow % NTOK) * Ndim + ncol];
        if (EPI == 5 && ncol < INNER) v *= QSCALE;
        if (OB)
          Cb[(size_t)mrow * Ndim + ncol] = f2b(v);
        else
          Cf[(size_t)mrow * Ndim + ncol] = v;
      }
    }
  }
}

// ---------------------------------------------------------------------------
// LayerNorm over last dim (768), fp32 in -> bf16 out. One block per row.
__global__ __launch_bounds__(256) void ln_kernel(
    const float* __restrict__ x, const float* __restrict__ w,
    const float* __restrict__ b, unsigned short* __restrict__ y) {
  int row = blockIdx.x;
  const float* xr = x + (size_t)row * DMODEL;
  unsigned short* yr = y + (size_t)row * DMODEL;
  int tid = threadIdx.x;
  float v0 = xr[tid], v1 = xr[tid + 256], v2 = xr[tid + 512];
  float s = v0 + v1 + v2;
  __shared__ float red[4];
#pragma unroll
  for (int off = 32; off >= 1; off >>= 1) s += __shfl_xor(s, off, 64);
  if ((tid & 63) == 0) red[tid >> 6] = s;
  __syncthreads();
  float mean = (red[0] + red[1] + red[2] + red[3]) * (1.0f / DMODEL);
  float d0 = v0 - mean, d1 = v1 - mean, d2 = v2 - mean;
  float sq = d0 * d0 + d1 * d1 + d2 * d2;
  __syncthreads();
#pragma unroll
  for (int off = 32; off >= 1; off >>= 1) sq += __shfl_xor(sq, off, 64);
  if ((tid & 63) == 0) red[tid >> 6] = sq;
  __syncthreads();
  float var = (red[0] + red[1] + red[2] + red[3]) * (1.0f / DMODEL);
  float rs = rsqrtf(var + LNEPS);
  yr[tid] = f2b(d0 * rs * w[tid] + b[tid]);
  yr[tid + 256] = f2b(d1 * rs * w[tid + 256] + b[tid + 256]);
  yr[tid + 512] = f2b(d2 * rs * w[tid + 512] + b[tid + 512]);
}

// ---------------------------------------------------------------------------
// MFMA flash attention. Block = (128 q-rows, head, batch); 4 waves x 32 q.
// S^T = K @ Q^T (C/D col = q), online softmax via in-wave shuffles, P packed
// bf16 into per-wave LDS in A-fragment layout, O = P @ V with pre-transposed
// V (vtg). Q pre-scaled by QSCALE in qkv GEMM -> softmax uses native exp2.
__global__ __launch_bounds__(256) void attn_kernel(
    const unsigned short* __restrict__ qkv,
    const unsigned short* __restrict__ vtg, unsigned short* __restrict__ o) {
  __shared__ __align__(16) unsigned short Ks[64 * PSTR];
  __shared__ __align__(16) unsigned short Vs[64 * PSTR];
  __shared__ __align__(16) unsigned short Pl[4][32 * PSTR];
  int tid = threadIdx.x;
  int lane = tid & 63, wv = tid >> 6;
  int quad = lane >> 4, lr = lane & 15;
  int q0 = blockIdx.x * 128, hh = blockIdx.y, bb = blockIdx.z;

  const unsigned short* qg =
      qkv + (size_t)(bb * NTOK + q0 + wv * 32) * QKVS + hh * DHEAD;
  const unsigned short* kg =
      qkv + (size_t)(bb * NTOK) * QKVS + INNER + hh * DHEAD;
  const unsigned short* vg = vtg + (size_t)(bb * HEADS + hh) * DHEAD * NTOK;
  unsigned short* Pw = Pl[wv];

  int srow = lane >> 3, soff = (lane & 7) * 8;

#pragma unroll
  for (int p = 0; p < 4; ++p) {
    int r = p * 8 + srow;
    *(int4*)(Pw + r * PSTR + soff) =
        *(const int4*)(qg + (size_t)r * QKVS + soff);
  }
  short8 qf[2][2];
#pragma unroll
  for (int n = 0; n < 2; ++n)
#pragma unroll
    for (int s = 0; s < 2; ++s)
      qf[n][s] =
          *(const short8*)(Pw + (n * 16 + lr) * PSTR + s * 32 + quad * 8);

  v4f oac[2][4] = {};
  float m_i[2] = {-1e30f, -1e30f};
  float l_i[2] = {0.f, 0.f};

  for (int t = 0; t < NTOK / 64; ++t) {
    __syncthreads();
#pragma unroll
    for (int p = 0; p < 2; ++p) {
      int r = wv * 16 + p * 8 + srow;
      *(int4*)(Ks + r * PSTR + soff) =
          *(const int4*)(kg + (size_t)(t * 64 + r) * QKVS + soff);
      *(int4*)(Vs + r * PSTR + soff) =
          *(const int4*)(vg + (size_t)r * NTOK + t * 64 + soff);
    }
    __syncthreads();

    v4f sac[4][2] = {};
#pragma unroll
    for (int s = 0; s < 2; ++s) {
      short8 kf[4];
#pragma unroll
      for (int mt = 0; mt < 4; ++mt)
        kf[mt] =
            *(const short8*)(Ks + (mt * 16 + lr) * PSTR + s * 32 + quad * 8);
#pragma unroll
      for (int mt = 0; mt < 4; ++mt)
#pragma unroll
        for (int n = 0; n < 2; ++n)
          sac[mt][n] = __builtin_amdgcn_mfma_f32_16x16x32_bf16(
              kf[mt], qf[n][s], sac[mt][n], 0, 0, 0);
    }

#pragma unroll
    for (int n = 0; n < 2; ++n) {
      float mx = -1e30f;
#pragma unroll
      for (int mt = 0; mt < 4; ++mt)
#pragma unroll
        for (int r = 0; r < 4; ++r) mx = fmaxf(mx, sac[mt][n][r]);
      mx = fmaxf(mx, __shfl_xor(mx, 16, 64));
      mx = fmaxf(mx, __shfl_xor(mx, 32, 64));
      float mnew = fmaxf(m_i[n], mx);
      float alpha = __builtin_amdgcn_exp2f(m_i[n] - mnew);
      m_i[n] = mnew;
      float sum = 0.f;
#pragma unroll
      for (int mt = 0; mt < 4; ++mt) {
#pragma unroll
        for (int r = 0; r < 4; ++r) {
          float p = __builtin_amdgcn_exp2f(sac[mt][n][r] - mnew);
          sac[mt][n][r] = p;
          sum += p;
        }
        *(uint2*)(Pw + (n * 16 + lr) * PSTR + mt * 16 + quad * 4) =
            make_uint2(pkrh(sac[mt][n][0], sac[mt][n][1]),
                       pkrh(sac[mt][n][2], sac[mt][n][3]));
      }
      sum += __shfl_xor(sum, 16, 64);
      sum += __shfl_xor(sum, 32, 64);
      l_i[n] = l_i[n] * alpha + sum;
#pragma unroll
      for (int r = 0; r < 4; ++r) {
        float ao = __shfl(alpha, quad * 4 + r, 64);
#pragma unroll
        for (int j = 0; j < 4; ++j) oac[n][j][r] *= ao;
      }
    }

#pragma unroll
    for (int s = 0; s < 2; ++s) {
      short8 pf[2], vf[4];
#pragma unroll
      for (int i = 0; i < 2; ++i)
        pf[i] =
            *(const short8*)(Pw + (i * 16 + lr) * PSTR + s * 32 + quad * 8);
#pragma unroll
      for (int j = 0; j < 4; ++j)
        vf[j] =
            *(const short8*)(Vs + (j * 16 + lr) * PSTR + s * 32 + quad * 8);
#pragma unroll
      for (int i = 0; i < 2; ++i)
#pragma unroll
        for (int j = 0; j < 4; ++j)
          oac[i][j] = __builtin_amdgcn_mfma_f32_16x16x32_bf16(
              pf[i], vf[j], oac[i][j], 0, 0, 0);
    }
  }

  unsigned short* ob =
      o + (size_t)(bb * NTOK + q0 + wv * 32) * INNER + hh * DHEAD;
#pragma unroll
  for (int i = 0; i < 2; ++i) {
    float inv = 1.0f / l_i[i];
#pragma unroll
    for (int r = 0; r < 4; ++r) {
      float il = __shfl(inv, quad * 4 + r, 64);
      int row = i * 16 + quad * 4 + r;
#pragma unroll
      for (int j = 0; j < 4; ++j)
        ob[(size_t)row * INNER + 16 * j + lr] = f2b(oac[i][j][r] * il);
    }
  }
}

// ---------------------------------------------------------------------------
extern "C" void kernel_launch(void* const* d_in, const int* in_sizes, int n_in,
                              void* d_out, int out_size, void* d_ws,
                              size_t ws_size, hipStream_t stream) {
  const float* x      = (const float*)d_in[0];
  const float* w_conv = (const float*)d_in[1];
  const float* b_conv = (const float*)d_in[2];
  const float* pos    = (const float*)d_in[3];
  const float* ln1w   = (const float*)d_in[4];
  const float* ln1b   = (const float*)d_in[5];
  const float* qkvw   = (const float*)d_in[6];
  const float* outw   = (const float*)d_in[7];
  const float* outb   = (const float*)d_in[8];
  const float* ln2w   = (const float*)d_in[9];
  const float* ln2b   = (const float*)d_in[10];
  const float* w1     = (const float*)d_in[11];
  const float* b1     = (const float*)d_in[12];
  const float* w2     = (const float*)d_in[13];
  const float* b2     = (const float*)d_in[14];

  char* ws = (char*)d_ws;
  float* outp = (float*)d_out;
  dim3 blk(256);

  // Common buffers
  float* h            = (float*)(ws + 0);                 // 25,165,824 B
  unsigned short* big = (unsigned short*)(ws + 25165824); // 50,331,648 B
  unsigned short* y   = (unsigned short*)(ws + 75497472); // 12,582,912 B

  // Batched-weight layout (needs 214,204,416 B); fallback = per-layer.
  const size_t NEEDED = 214204416;
  bool batched = ws_size >= NEEDED;

  unsigned short *vt, *wc, *wqa, *woa, *w1a, *w2a;  // batched
  unsigned short *wq_f, *wo_f, *w1_f, *w2_f;        // fallback per-layer
  if (batched) {
    vt  = (unsigned short*)(ws + 88080384);   // 12,582,912 B
    wc  = (unsigned short*)(ws + 100663296);  //    294,912 B
    wqa = (unsigned short*)(ws + 100958208);  // 28,311,552 B
    woa = (unsigned short*)(ws + 129269760);  //  9,437,184 B
    w1a = (unsigned short*)(ws + 138706944);  // 37,748,736 B
    w2a = (unsigned short*)(ws + 176455680);  // 37,748,736 B
    wq_f = wo_f = w1_f = w2_f = nullptr;
  } else {
    wq_f = (unsigned short*)(ws + 88080384);  //  3,538,944 B
    wo_f = (unsigned short*)(ws + 91619328);  //  1,179,648 B
    w1_f = (unsigned short*)(ws + 92798976);  //  4,718,592 B
    w2_f = (unsigned short*)(ws + 97517568);  //  4,718,592 B
    wc   = (unsigned short*)(ws + 102236160); //    294,912 B
    vt   = (unsigned short*)(ws + 102531072); // 12,582,912 B
    wqa = woa = w1a = w2a = nullptr;
  }

  cast_kernel<<<dim3((DMODEL * KPATCH + 255) / 256), blk, 0, stream>>>(
      w_conv, wc, DMODEL * KPATCH);
  im2col_kernel<<<dim3((MROWS * KPATCH + 255) / 256), blk, 0, stream>>>(x, big);
  // patch embed: [8192,192] @ wc[768,192]^T + b_conv + pos -> h fp32
  mfma_gemm_kernel<4, 0, 64>
      <<<dim3((MROWS / 64) * (DMODEL / 128)), blk, 0, stream>>>(
          big, wc, b_conv, pos, h, MROWS, DMODEL, KPATCH);

  if (batched) {  // all-layer weight transposes, one dispatch per type
    transpose_cast_kernel<<<dim3(QKVS / 32, DMODEL / 32, DEPTH), blk, 0,
                            stream>>>(qkvw, wqa, DMODEL, QKVS);
    transpose_cast_kernel<<<dim3(DMODEL / 32, INNER / 32, DEPTH), blk, 0,
                            stream>>>(outw, woa, INNER, DMODEL);
    transpose_cast_kernel<<<dim3(MLPDIM / 32, DMODEL / 32, DEPTH), blk, 0,
                            stream>>>(w1, w1a, DMODEL, MLPDIM);
    transpose_cast_kernel<<<dim3(DMODEL / 32, MLPDIM / 32, DEPTH), blk, 0,
                            stream>>>(w2, w2a, MLPDIM, DMODEL);
  }

  for (int l = 0; l < DEPTH; ++l) {
    unsigned short* wq = batched ? wqa + (size_t)l * DMODEL * QKVS : wq_f;
    unsigned short* wo = batched ? woa + (size_t)l * INNER * DMODEL : wo_f;
    unsigned short* w1t = batched ? w1a + (size_t)l * DMODEL * MLPDIM : w1_f;
    unsigned short* w2t = batched ? w2a + (size_t)l * MLPDIM * DMODEL : w2_f;
    if (!batched) {
      transpose_cast_kernel<<<dim3(QKVS / 32, DMODEL / 32), blk, 0, stream>>>(
          qkvw + (size_t)l * DMODEL * QKVS, wq, DMODEL, QKVS);
    }
    ln_kernel<<<dim3(MROWS), blk, 0, stream>>>(h, ln1w + l * DMODEL,
                                               ln1b + l * DMODEL, y);
    mfma_gemm_kernel<5, 1, 128>
        <<<dim3((MROWS / 128) * (QKVS / 128)), blk, 0, stream>>>(
            y, wq, nullptr, nullptr, big, MROWS, QKVS, DMODEL);
    vtrans_kernel<<<dim3(NTOK / 32, DHEAD / 32, BATCH * HEADS), blk, 0,
                    stream>>>(big, vt);
    attn_kernel<<<dim3(NTOK / 128, HEADS, BATCH), blk, 0, stream>>>(big, vt, y);
    if (!batched) {
      transpose_cast_kernel<<<dim3(DMODEL / 32, INNER / 32), blk, 0, stream>>>(
          outw + (size_t)l * INNER * DMODEL, wo, INNER, DMODEL);
    }
    mfma_gemm_kernel<2, 0, 64>
        <<<dim3((MROWS / 64) * (DMODEL / 128)), blk, 0, stream>>>(
            y, wo, outb + l * DMODEL, h, h, MROWS, DMODEL, INNER);
    ln_kernel<<<dim3(MROWS), blk, 0, stream>>>(h, ln2w + l * DMODEL,
                                               ln2b + l * DMODEL, y);
    if (!batched) {
      transpose_cast_kernel<<<dim3(MLPDIM / 32, DMODEL / 32), blk, 0, stream>>>(
          w1 + (size_t)l * DMODEL * MLPDIM, w1t, DMODEL, MLPDIM);
    }
    mfma_gemm_kernel<3, 1, 128>
        <<<dim3((MROWS / 128) * (MLPDIM / 128)), blk, 0, stream>>>(
            y, w1t, b1 + l * MLPDIM, nullptr, big, MROWS, MLPDIM, DMODEL);
    if (!batched) {
      transpose_cast_kernel<<<dim3(DMODEL / 32, MLPDIM / 32), blk, 0, stream>>>(
          w2 + (size_t)l * MLPDIM * DMODEL, w2t, MLPDIM, DMODEL);
    }
    float* dst = (l == DEPTH - 1) ? outp : h;
    mfma_gemm_kernel<2, 0, 64>
        <<<dim3((MROWS / 64) * (DMODEL / 128)), blk, 0, stream>>>(
            big, w2t, b2 + l * DMODEL, h, dst, MROWS, DMODEL, MLPDIM);
  }
}

// Round 8
// 2214.856 us; speedup vs baseline: 2.6599x; 1.1482x over previous
//
#include <hip/hip_runtime.h>
#include <math.h>

// Problem constants (ViT-Base-ish)
#define BATCH 8
#define CIN 3
#define HIMG 256
#define WIMG 256
#define PATCH 8
#define DMODEL 768
#define DEPTH 8
#define HEADS 12
#define DHEAD 64
#define MLPDIM 3072
#define NTOK 1024              // (256/8)^2
#define INNER 768              // HEADS*DHEAD
#define MROWS (BATCH * NTOK)   // 8192
#define QKVS (3 * INNER)       // 2304
#define KPATCH (CIN * PATCH * PATCH)  // 192
#define LNEPS 1e-5f
#define PSTR 72                // attn LDS row stride (16B-aligned, conflict-safe)
// 0.125 (dh^-0.5) * log2(e): folded into Q so softmax uses exp2 (v_exp_f32)
#define QSCALE 0.18033688011112042f

typedef __attribute__((ext_vector_type(8))) short short8;  // 8 bf16 (4 VGPRs)
typedef __attribute__((ext_vector_type(4))) float v4f;     // MFMA accumulator

__device__ __forceinline__ float b2f(unsigned short u) {
  union { unsigned int i; float f; } x;
  x.i = (unsigned int)u << 16;
  return x.f;
}
__device__ __forceinline__ unsigned short f2b(float f) {
  union { float f; unsigned int i; } x;
  x.f = f;
  unsigned int r = x.i + 0x7FFFu + ((x.i >> 16) & 1u);  // RNE
  return (unsigned short)(r >> 16);
}
// pack 2 fp32 -> 2 bf16 in one u32, round-half-up (cheap: 4 VALU)
__device__ __forceinline__ unsigned int pkrh(float a, float b) {
  union { float f; unsigned int u; } x, y;
  x.f = a; y.f = b;
  return ((x.u + 0x8000u) >> 16) | ((y.u + 0x8000u) & 0xFFFF0000u);
}

// async 16B/lane global->LDS (wave-uniform LDS base + lane*16B)
#define GLL(gp, lp)                                                     \
  __builtin_amdgcn_global_load_lds(                                     \
      (const __attribute__((address_space(1))) void*)(gp),              \
      (__attribute__((address_space(3))) void*)(lp), 16, 0, 0)

// ---------------------------------------------------------------------------
// elementwise fp32 -> bf16 cast (w_conv: [768,192] already [N,K])
__global__ __launch_bounds__(256) void cast_kernel(
    const float* __restrict__ src, unsigned short* __restrict__ dst, int n) {
  int i = blockIdx.x * 256 + threadIdx.x;
  if (i < n) dst[i] = f2b(src[i]);
}

// transpose-cast: src fp32 [R,C] -> dst bf16 [C,R]. R,C multiples of 32.
// blockIdx.z selects a layer: both src and dst advance by R*C elements.
__global__ __launch_bounds__(256) void transpose_cast_kernel(
    const float* __restrict__ src, unsigned short* __restrict__ dst, int R,
    int C) {
  __shared__ unsigned short t[32][33];
  src += (size_t)blockIdx.z * R * C;
  dst += (size_t)blockIdx.z * R * C;
  int c0 = blockIdx.x * 32, r0 = blockIdx.y * 32;
  int tx = threadIdx.x & 31, ty = threadIdx.x >> 5;  // 32 x 8
#pragma unroll
  for (int u = 0; u < 4; ++u) {
    int r = r0 + ty + u * 8;
    t[ty + u * 8][tx] = f2b(src[(size_t)r * C + c0 + tx]);
  }
  __syncthreads();
#pragma unroll
  for (int u = 0; u < 4; ++u) {
    int c = c0 + ty + u * 8;
    dst[(size_t)c * R + r0 + tx] = t[tx][ty + u * 8];
  }
}

// V transpose per layer: qkv bf16 [MROWS][QKVS] V-part -> vt [B*H][64][1024]
__global__ __launch_bounds__(256) void vtrans_kernel(
    const unsigned short* __restrict__ qkv, unsigned short* __restrict__ vt) {
  __shared__ unsigned short t[32][33];
  int k0 = blockIdx.x * 32;   // key tile
  int d0 = blockIdx.y * 32;   // dim tile within head
  int bh = blockIdx.z;        // b*HEADS+h
  int b = bh / HEADS, h = bh % HEADS;
  int tx = threadIdx.x & 31, ty = threadIdx.x >> 5;
  const unsigned short* src =
      qkv + (size_t)(b * NTOK) * QKVS + 2 * INNER + h * DHEAD;
#pragma unroll
  for (int u = 0; u < 4; ++u)
    t[ty + u * 8][tx] = src[(size_t)(k0 + ty + u * 8) * QKVS + d0 + tx];
  __syncthreads();
  unsigned short* dst = vt + ((size_t)bh * DHEAD + d0) * NTOK + k0;
#pragma unroll
  for (int u = 0; u < 4; ++u)
    dst[(size_t)(ty + u * 8) * NTOK + tx] = t[tx][ty + u * 8];
}

// im2col -> bf16: x [B,C,H,W] -> A [MROWS, 192]
__global__ __launch_bounds__(256) void im2col_kernel(
    const float* __restrict__ x, unsigned short* __restrict__ A) {
  int idx = blockIdx.x * 256 + threadIdx.x;
  if (idx >= MROWS * KPATCH) return;
  int m = idx / KPATCH, k = idx % KPATCH;
  int b = m / NTOK, n = m % NTOK;
  int ph = n / 32, pw = n % 32;
  int c = k / 64, r = k % 64;
  int py = r / 8, px = r % 8;
  A[idx] =
      f2b(x[((size_t)(b * CIN + c) * HIMG + ph * 8 + py) * WIMG + pw * 8 + px]);
}

// ---------------------------------------------------------------------------
// bf16 MFMA GEMM: C[M,N] = A[M,K] @ Bt[N,K]^T, fp32 accumulate.
// Proven GLL 2-barrier skeleton + two changes this round:
//  * BK=64 (rows of 64 elems = 128B): halves barrier/vmcnt-drain count.
//  * XOR-swizzled LDS: GLL dest is fixed (base+lane*16B) so we permute the
//    global SOURCE col-group per lane (g^(row&7)); fragment reads use col
//    ((s*4+quad)^(lr&7))*8 -> a quad's 16 lanes hit all 32 banks (2-way
//    lr/lr+8 alias only = free). Kills the 8-way b128 conflicts (7.1M/disp).
// MT=128: 2x2 quadrants of 64x64/wave. MT=64: 32x64/wave, N=768 GEMMs get
// 768 blocks = 3/CU. 1-D grid, XCD swizzle (bid&7=XCD, n fastest).
// EPI: 0 none; 2 +bias+res(fp32); 3 +bias fast-GELU; 4 +bias+pos_emb;
//      5 qkv (Q cols * QSCALE). OB: bf16 out.
template <int EPI, int OB, int MT>
__global__ __launch_bounds__(256) void mfma_gemm_kernel(
    const unsigned short* __restrict__ Ag, const unsigned short* __restrict__ Bt,
    const float* __restrict__ bias, const float* __restrict__ res,
    void* __restrict__ Cg, int Mdim, int Ndim, int Kdim) {
  constexpr int MI = MT / 32;               // m fragment tiles per wave (4|2)
  constexpr int RA = MT / 4;                // A rows staged per wave (32|16)
  constexpr int NCA = RA / 8;               // A GLL chunks per wave (4|2)
  __shared__ __align__(16) unsigned short Asm[MT * 64];
  __shared__ __align__(16) unsigned short Bsm[128 * 64];
  int tid = threadIdx.x;
  int lane = tid & 63, wv = tid >> 6;

  // XCD-aware swizzle (1-D grid of (M/MT)*(N/128) blocks)
  int Nt = Ndim / 128;
  int mchunk = (Mdim / MT) >> 3;
  int bid = blockIdx.x;
  int xcd = bid & 7;
  int j = bid >> 3;
  int m0 = (xcd * mchunk + j / Nt) * MT;
  int n0 = (j % Nt) * 128;

  v4f acc[MI][4] = {};

  // staging: chunk = 8 rows x 64 elems (1KB); lane -> row lane>>3,
  // source col-group XOR-permuted by row&7 (dest is fixed lane*16B).
  int sr8 = lane >> 3;
  int sc8 = ((lane & 7) ^ sr8) * 8;
  const unsigned short* Aw = Ag + (size_t)(m0 + RA * wv + sr8) * Kdim + sc8;
  const unsigned short* Bw = Bt + (size_t)(n0 + 32 * wv + sr8) * Kdim + sc8;
  unsigned short* As0 = Asm + (RA * wv) * 64;
  unsigned short* Bs0 = Bsm + (32 * wv) * 64;

  int quad = lane >> 4, lr = lane & 15;
  int fr0 = (wv >> 1) * (MI * 16);
  int fc0 = (wv & 1) * 64;
  int xcol = (quad ^ (lr & 7)) * 8;  // swizzled col offset (s=0); s=1: ^32
  const unsigned short* Afr = Asm + (fr0 + lr) * 64;
  const unsigned short* Bfr = Bsm + (fc0 + lr) * 64;

  for (int k0 = 0; k0 < Kdim; k0 += 64) {
#pragma unroll
    for (int c = 0; c < NCA; ++c)
      GLL(Aw + k0 + (size_t)(8 * c) * Kdim, As0 + c * 8 * 64);
#pragma unroll
    for (int c = 0; c < 4; ++c)
      GLL(Bw + k0 + (size_t)(8 * c) * Kdim, Bs0 + c * 8 * 64);
    __syncthreads();
#pragma unroll
    for (int s = 0; s < 2; ++s) {
      int xo = xcol ^ (s * 32);
      short8 af[MI], bf[4];
#pragma unroll
      for (int i = 0; i < MI; ++i)
        af[i] = *(const short8*)(Afr + i * 16 * 64 + xo);
#pragma unroll
      for (int n = 0; n < 4; ++n)
        bf[n] = *(const short8*)(Bfr + n * 16 * 64 + xo);
#pragma unroll
      for (int i = 0; i < MI; ++i)
#pragma unroll
        for (int n = 0; n < 4; ++n)
          acc[i][n] = __builtin_amdgcn_mfma_f32_16x16x32_bf16(
              af[i], bf[n], acc[i][n], 0, 0, 0);
    }
    __syncthreads();
  }

  // epilogue: C/D layout col=lane&15, row=quad*4+reg
  float* Cf = (float*)Cg;
  unsigned short* Cb = (unsigned short*)Cg;
#pragma unroll
  for (int i = 0; i < MI; ++i) {
#pragma unroll
    for (int n = 0; n < 4; ++n) {
      int ncol = n0 + fc0 + 16 * n + lr;
#pragma unroll
      for (int reg = 0; reg < 4; ++reg) {
        int mrow = m0 + fr0 + 16 * i + quad * 4 + reg;
        float v = acc[i][n][reg];
        if (EPI == 2 || EPI == 3 || EPI == 4) v += bias[ncol];
        if (EPI == 2) v += res[(size_t)mrow * Ndim + ncol];
        if (EPI == 3) {
          // gelu(x) ~= x * sigmoid(2*0.79788456*(x + 0.044715 x^3)); hw exp2
          float u = v * (0.7978845608028654f + 0.035677408136300125f * v * v);
          float a = fminf(fmaxf(u * 2.8853900817779268f, -60.f), 60.f);
          float E = __builtin_amdgcn_exp2f(a);
          v = v * E * __builtin_amdgcn_rcpf(E + 1.0f);
        }
        if (EPI == 4) v += res[(size_t)(mrow % NTOK) * Ndim + ncol];
        if (EPI == 5 && ncol < INNER) v *= QSCALE;
        if (OB)
          Cb[(size_t)mrow * Ndim + ncol] = f2b(v);
        else
          Cf[(size_t)mrow * Ndim + ncol] = v;
      }
    }
  }
}

// ---------------------------------------------------------------------------
// LayerNorm over last dim (768), fp32 in -> bf16 out. One block per row.
__global__ __launch_bounds__(256) void ln_kernel(
    const float* __restrict__ x, const float* __restrict__ w,
    const float* __restrict__ b, unsigned short* __restrict__ y) {
  int row = blockIdx.x;
  const float* xr = x + (size_t)row * DMODEL;
  unsigned short* yr = y + (size_t)row * DMODEL;
  int tid = threadIdx.x;
  float v0 = xr[tid], v1 = xr[tid + 256], v2 = xr[tid + 512];
  float s = v0 + v1 + v2;
  __shared__ float red[4];
#pragma unroll
  for (int off = 32; off >= 1; off >>= 1) s += __shfl_xor(s, off, 64);
  if ((tid & 63) == 0) red[tid >> 6] = s;
  __syncthreads();
  float mean = (red[0] + red[1] + red[2] + red[3]) * (1.0f / DMODEL);
  float d0 = v0 - mean, d1 = v1 - mean, d2 = v2 - mean;
  float sq = d0 * d0 + d1 * d1 + d2 * d2;
  __syncthreads();
#pragma unroll
  for (int off = 32; off >= 1; off >>= 1) sq += __shfl_xor(sq, off, 64);
  if ((tid & 63) == 0) red[tid >> 6] = sq;
  __syncthreads();
  float var = (red[0] + red[1] + red[2] + red[3]) * (1.0f / DMODEL);
  float rs = rsqrtf(var + LNEPS);
  yr[tid] = f2b(d0 * rs * w[tid] + b[tid]);
  yr[tid + 256] = f2b(d1 * rs * w[tid + 256] + b[tid + 256]);
  yr[tid + 512] = f2b(d2 * rs * w[tid + 512] + b[tid + 512]);
}

// ---------------------------------------------------------------------------
// MFMA flash attention. Block = (128 q-rows, head, batch); 4 waves x 32 q.
// S^T = K @ Q^T (C/D col = q), online softmax via in-wave shuffles, P packed
// bf16 into per-wave LDS in A-fragment layout, O = P @ V with pre-transposed
// V (vtg). Q pre-scaled by QSCALE in qkv GEMM -> softmax uses native exp2.
// PSTR=72 rows: frag reads conflict-free (lr*4 bank stride).
__global__ __launch_bounds__(256) void attn_kernel(
    const unsigned short* __restrict__ qkv,
    const unsigned short* __restrict__ vtg, unsigned short* __restrict__ o) {
  __shared__ __align__(16) unsigned short Ks[64 * PSTR];
  __shared__ __align__(16) unsigned short Vs[64 * PSTR];
  __shared__ __align__(16) unsigned short Pl[4][32 * PSTR];
  int tid = threadIdx.x;
  int lane = tid & 63, wv = tid >> 6;
  int quad = lane >> 4, lr = lane & 15;
  int q0 = blockIdx.x * 128, hh = blockIdx.y, bb = blockIdx.z;

  const unsigned short* qg =
      qkv + (size_t)(bb * NTOK + q0 + wv * 32) * QKVS + hh * DHEAD;
  const unsigned short* kg =
      qkv + (size_t)(bb * NTOK) * QKVS + INNER + hh * DHEAD;
  const unsigned short* vg = vtg + (size_t)(bb * HEADS + hh) * DHEAD * NTOK;
  unsigned short* Pw = Pl[wv];

  int srow = lane >> 3, soff = (lane & 7) * 8;

#pragma unroll
  for (int p = 0; p < 4; ++p) {
    int r = p * 8 + srow;
    *(int4*)(Pw + r * PSTR + soff) =
        *(const int4*)(qg + (size_t)r * QKVS + soff);
  }
  short8 qf[2][2];
#pragma unroll
  for (int n = 0; n < 2; ++n)
#pragma unroll
    for (int s = 0; s < 2; ++s)
      qf[n][s] =
          *(const short8*)(Pw + (n * 16 + lr) * PSTR + s * 32 + quad * 8);

  v4f oac[2][4] = {};
  float m_i[2] = {-1e30f, -1e30f};
  float l_i[2] = {0.f, 0.f};

  for (int t = 0; t < NTOK / 64; ++t) {
    __syncthreads();
#pragma unroll
    for (int p = 0; p < 2; ++p) {
      int r = wv * 16 + p * 8 + srow;
      *(int4*)(Ks + r * PSTR + soff) =
          *(const int4*)(kg + (size_t)(t * 64 + r) * QKVS + soff);
      *(int4*)(Vs + r * PSTR + soff) =
          *(const int4*)(vg + (size_t)r * NTOK + t * 64 + soff);
    }
    __syncthreads();

    v4f sac[4][2] = {};
#pragma unroll
    for (int s = 0; s < 2; ++s) {
      short8 kf[4];
#pragma unroll
      for (int mt = 0; mt < 4; ++mt)
        kf[mt] =
            *(const short8*)(Ks + (mt * 16 + lr) * PSTR + s * 32 + quad * 8);
#pragma unroll
      for (int mt = 0; mt < 4; ++mt)
#pragma unroll
        for (int n = 0; n < 2; ++n)
          sac[mt][n] = __builtin_amdgcn_mfma_f32_16x16x32_bf16(
              kf[mt], qf[n][s], sac[mt][n], 0, 0, 0);
    }

#pragma unroll
    for (int n = 0; n < 2; ++n) {
      float mx = -1e30f;
#pragma unroll
      for (int mt = 0; mt < 4; ++mt)
#pragma unroll
        for (int r = 0; r < 4; ++r) mx = fmaxf(mx, sac[mt][n][r]);
      mx = fmaxf(mx, __shfl_xor(mx, 16, 64));
      mx = fmaxf(mx, __shfl_xor(mx, 32, 64));
      float mnew = fmaxf(m_i[n], mx);
      float alpha = __builtin_amdgcn_exp2f(m_i[n] - mnew);
      m_i[n] = mnew;
      float sum = 0.f;
#pragma unroll
      for (int mt = 0; mt < 4; ++mt) {
#pragma unroll
        for (int r = 0; r < 4; ++r) {
          float p = __builtin_amdgcn_exp2f(sac[mt][n][r] - mnew);
          sac[mt][n][r] = p;
          sum += p;
        }
        *(uint2*)(Pw + (n * 16 + lr) * PSTR + mt * 16 + quad * 4) =
            make_uint2(pkrh(sac[mt][n][0], sac[mt][n][1]),
                       pkrh(sac[mt][n][2], sac[mt][n][3]));
      }
      sum += __shfl_xor(sum, 16, 64);
      sum += __shfl_xor(sum, 32, 64);
      l_i[n] = l_i[n] * alpha + sum;
#pragma unroll
      for (int r = 0; r < 4; ++r) {
        float ao = __shfl(alpha, quad * 4 + r, 64);
#pragma unroll
        for (int j = 0; j < 4; ++j) oac[n][j][r] *= ao;
      }
    }

#pragma unroll
    for (int s = 0; s < 2; ++s) {
      short8 pf[2], vf[4];
#pragma unroll
      for (int i = 0; i < 2; ++i)
        pf[i] =
            *(const short8*)(Pw + (i * 16 + lr) * PSTR + s * 32 + quad * 8);
#pragma unroll
      for (int j = 0; j < 4; ++j)
        vf[j] =
            *(const short8*)(Vs + (j * 16 + lr) * PSTR + s * 32 + quad * 8);
#pragma unroll
      for (int i = 0; i < 2; ++i)
#pragma unroll
        for (int j = 0; j < 4; ++j)
          oac[i][j] = __builtin_amdgcn_mfma_f32_16x16x32_bf16(
              pf[i], vf[j], oac[i][j], 0, 0, 0);
    }
  }

  unsigned short* ob =
      o + (size_t)(bb * NTOK + q0 + wv * 32) * INNER + hh * DHEAD;
#pragma unroll
  for (int i = 0; i < 2; ++i) {
    float inv = 1.0f / l_i[i];
#pragma unroll
    for (int r = 0; r < 4; ++r) {
      float il = __shfl(inv, quad * 4 + r, 64);
      int row = i * 16 + quad * 4 + r;
#pragma unroll
      for (int j = 0; j < 4; ++j)
        ob[(size_t)row * INNER + 16 * j + lr] = f2b(oac[i][j][r] * il);
    }
  }
}

// ---------------------------------------------------------------------------
extern "C" void kernel_launch(void* const* d_in, const int* in_sizes, int n_in,
                              void* d_out, int out_size, void* d_ws,
                              size_t ws_size, hipStream_t stream) {
  const float* x      = (const float*)d_in[0];
  const float* w_conv = (const float*)d_in[1];
  const float* b_conv = (const float*)d_in[2];
  const float* pos    = (const float*)d_in[3];
  const float* ln1w   = (const float*)d_in[4];
  const float* ln1b   = (const float*)d_in[5];
  const float* qkvw   = (const float*)d_in[6];
  const float* outw   = (const float*)d_in[7];
  const float* outb   = (const float*)d_in[8];
  const float* ln2w   = (const float*)d_in[9];
  const float* ln2b   = (const float*)d_in[10];
  const float* w1     = (const float*)d_in[11];
  const float* b1     = (const float*)d_in[12];
  const float* w2     = (const float*)d_in[13];
  const float* b2     = (const float*)d_in[14];

  char* ws = (char*)d_ws;
  float* outp = (float*)d_out;
  dim3 blk(256);

  // Common buffers
  float* h            = (float*)(ws + 0);                 // 25,165,824 B
  unsigned short* big = (unsigned short*)(ws + 25165824); // 50,331,648 B
  unsigned short* y   = (unsigned short*)(ws + 75497472); // 12,582,912 B

  // Batched-weight layout (needs 214,204,416 B); fallback = per-layer.
  const size_t NEEDED = 214204416;
  bool batched = ws_size >= NEEDED;

  unsigned short *vt, *wc, *wqa, *woa, *w1a, *w2a;  // batched
  unsigned short *wq_f, *wo_f, *w1_f, *w2_f;        // fallback per-layer
  if (batched) {
    vt  = (unsigned short*)(ws + 88080384);   // 12,582,912 B
    wc  = (unsigned short*)(ws + 100663296);  //    294,912 B
    wqa = (unsigned short*)(ws + 100958208);  // 28,311,552 B
    woa = (unsigned short*)(ws + 129269760);  //  9,437,184 B
    w1a = (unsigned short*)(ws + 138706944);  // 37,748,736 B
    w2a = (unsigned short*)(ws + 176455680);  // 37,748,736 B
    wq_f = wo_f = w1_f = w2_f = nullptr;
  } else {
    wq_f = (unsigned short*)(ws + 88080384);  //  3,538,944 B
    wo_f = (unsigned short*)(ws + 91619328);  //  1,179,648 B
    w1_f = (unsigned short*)(ws + 92798976);  //  4,718,592 B
    w2_f = (unsigned short*)(ws + 97517568);  //  4,718,592 B
    wc   = (unsigned short*)(ws + 102236160); //    294,912 B
    vt   = (unsigned short*)(ws + 102531072); // 12,582,912 B
    wqa = woa = w1a = w2a = nullptr;
  }

  cast_kernel<<<dim3((DMODEL * KPATCH + 255) / 256), blk, 0, stream>>>(
      w_conv, wc, DMODEL * KPATCH);
  im2col_kernel<<<dim3((MROWS * KPATCH + 255) / 256), blk, 0, stream>>>(x, big);
  // patch embed: [8192,192] @ wc[768,192]^T + b_conv + pos -> h fp32
  mfma_gemm_kernel<4, 0, 64>
      <<<dim3((MROWS / 64) * (DMODEL / 128)), blk, 0, stream>>>(
          big, wc, b_conv, pos, h, MROWS, DMODEL, KPATCH);

  if (batched) {  // all-layer weight transposes, one dispatch per type
    transpose_cast_kernel<<<dim3(QKVS / 32, DMODEL / 32, DEPTH), blk, 0,
                            stream>>>(qkvw, wqa, DMODEL, QKVS);
    transpose_cast_kernel<<<dim3(DMODEL / 32, INNER / 32, DEPTH), blk, 0,
                            stream>>>(outw, woa, INNER, DMODEL);
    transpose_cast_kernel<<<dim3(MLPDIM / 32, DMODEL / 32, DEPTH), blk, 0,
                            stream>>>(w1, w1a, DMODEL, MLPDIM);
    transpose_cast_kernel<<<dim3(DMODEL / 32, MLPDIM / 32, DEPTH), blk, 0,
                            stream>>>(w2, w2a, MLPDIM, DMODEL);
  }

  for (int l = 0; l < DEPTH; ++l) {
    unsigned short* wq = batched ? wqa + (size_t)l * DMODEL * QKVS : wq_f;
    unsigned short* wo = batched ? woa + (size_t)l * INNER * DMODEL : wo_f;
    unsigned short* w1t = batched ? w1a + (size_t)l * DMODEL * MLPDIM : w1_f;
    unsigned short* w2t = batched ? w2a + (size_t)l * MLPDIM * DMODEL : w2_f;
    if (!batched) {
      transpose_cast_kernel<<<dim3(QKVS / 32, DMODEL / 32), blk, 0, stream>>>(
          qkvw + (size_t)l * DMODEL * QKVS, wq, DMODEL, QKVS);
    }
    ln_kernel<<<dim3(MROWS), blk, 0, stream>>>(h, ln1w + l * DMODEL,
                                               ln1b + l * DMODEL, y);
    mfma_gemm_kernel<5, 1, 128>
        <<<dim3((MROWS / 128) * (QKVS / 128)), blk, 0, stream>>>(
            y, wq, nullptr, nullptr, big, MROWS, QKVS, DMODEL);
    vtrans_kernel<<<dim3(NTOK / 32, DHEAD / 32, BATCH * HEADS), blk, 0,
                    stream>>>(big, vt);
    attn_kernel<<<dim3(NTOK / 128, HEADS, BATCH), blk, 0, stream>>>(big, vt, y);
    if (!batched) {
      transpose_cast_kernel<<<dim3(DMODEL / 32, INNER / 32), blk, 0, stream>>>(
          outw + (size_t)l * INNER * DMODEL, wo, INNER, DMODEL);
    }
    mfma_gemm_kernel<2, 0, 64>
        <<<dim3((MROWS / 64) * (DMODEL / 128)), blk, 0, stream>>>(
            y, wo, outb + l * DMODEL, h, h, MROWS, DMODEL, INNER);
    ln_kernel<<<dim3(MROWS), blk, 0, stream>>>(h, ln2w + l * DMODEL,
                                               ln2b + l * DMODEL, y);
    if (!batched) {
      transpose_cast_kernel<<<dim3(MLPDIM / 32, DMODEL / 32), blk, 0, stream>>>(
          w1 + (size_t)l * DMODEL * MLPDIM, w1t, DMODEL, MLPDIM);
    }
    mfma_gemm_kernel<3, 1, 128>
        <<<dim3((MROWS / 128) * (MLPDIM / 128)), blk, 0, stream>>>(
            y, w1t, b1 + l * MLPDIM, nullptr, big, MROWS, MLPDIM, DMODEL);
    if (!batched) {
      transpose_cast_kernel<<<dim3(DMODEL / 32, MLPDIM / 32), blk, 0, stream>>>(
          w2 + (size_t)l * MLPDIM * DMODEL, w2t, MLPDIM, DMODEL);
    }
    float* dst = (l == DEPTH - 1) ? outp : h;
    mfma_gemm_kernel<2, 0, 64>
        <<<dim3((MROWS / 64) * (DMODEL / 128)), blk, 0, stream>>>(
            big, w2t, b2 + l * DMODEL, h, dst, MROWS, DMODEL, MLPDIM);
  }
}